// Round 2
// baseline (2330.698 us; speedup 1.0000x reference)
//
#include <hip/hip_runtime.h>
#include <stdint.h>

#define NN 5000
#define NE 80000
#define NF 128
#define NT 16
#define TN 10
#define NFW 3
#define NSK 10
#define TPB 256
#define NBT 16               // blocks per template
#define RPB 313              // ceil(NN/NBT)
#define NBLK (NT * NBT)      // 256 blocks

// ---------- workspace layout (bytes) ----------
#define OFF_DEG   0u         // 5000 ints
#define OFF_RP    20224u     // 5001 ints
#define OFF_CUR   40448u
#define OFF_COL   60672u     // 80000 ints -> 380672
#define OFF_FFS   380672u    // NT*16 floats -> 381696
#define OFF_BAR   381696u    // NT*16 u32 (barrier ctr per template, 64B apart) -> 382720
#define OFF_SABS  382720u    // NFW*NT floats (padded) -> 382976
#define OFF_DOTS  382976u    // NFW*NT*4 floats (padded) -> 384000
#define OFF_FIN   384000u    // NT*4 floats -> 384256
#define OFF_CS    384256u    // NFW*NSK*NT*16 floats = 30720 B -> 414976
#define OFF_Y     416000u    // NT*NN*8 u32 = 2,560,000 B
#define ZERO_INTS 8320       // ints from OFF_BAR to end of OFF_CS (33280 B)

// ---------- helpers ----------
__device__ __forceinline__ uint32_t bfb(float x) {
  uint32_t u = __float_as_uint(x);
  return (u + 0x7fffu + ((u >> 16) & 1u)) >> 16;
}
__device__ __forceinline__ uint32_t pk(float a, float b) { return bfb(a) | (bfb(b) << 16); }
__device__ __forceinline__ float ubl(uint32_t u) { return __uint_as_float(u << 16); }
__device__ __forceinline__ float ubh(uint32_t u) { return __uint_as_float(u & 0xffff0000u); }

__device__ __forceinline__ float aload(const float* p) {
  return __hip_atomic_load(p, __ATOMIC_RELAXED, __HIP_MEMORY_SCOPE_AGENT);
}

// per-template spin barrier: NBT blocks, monotonic counter, device-scope
__device__ __forceinline__ void tbar(unsigned* ctr, unsigned target) {
  __threadfence();
  __syncthreads();
  if (threadIdx.x == 0) {
    __hip_atomic_fetch_add(ctr, 1u, __ATOMIC_RELEASE, __HIP_MEMORY_SCOPE_AGENT);
    while (__hip_atomic_load(ctr, __ATOMIC_ACQUIRE, __HIP_MEMORY_SCOPE_AGENT) < target)
      __builtin_amdgcn_s_sleep(1);
  }
  __syncthreads();
  __threadfence();
}

// wave-reduce then one atomicAdd per wave
__device__ __forceinline__ void wred_atomic(float v, float* gaddr) {
  #pragma unroll
  for (int o = 32; o; o >>= 1) v += __shfl_xor(v, o, 64);
  if ((threadIdx.x & 63) == 0) atomicAdd(gaddr, v);
}

__device__ __forceinline__ void gatherG(const uint32_t* __restrict__ Yk,
                                        const int* __restrict__ colidx,
                                        int e0, int e1, float* acc) {
  for (int e = e0; e < e1; ++e) {
    int c = colidx[e];
    const uint32_t* r = Yk + (size_t)c * 8;
    uint4 A = *(const uint4*)r;
    uint2 B = *(const uint2*)(r + 4);
    acc[0] += ubl(A.x); acc[1] += ubh(A.x); acc[2] += ubl(A.y); acc[3] += ubh(A.y);
    acc[4] += ubl(A.z); acc[5] += ubh(A.z); acc[6] += ubl(A.w); acc[7] += ubh(A.w);
    acc[8] += ubl(B.x); acc[9] += ubh(B.x);
  }
}

__device__ __forceinline__ void ybuild_g(uint32_t* __restrict__ Yk, int r,
                                         const float* Trow, const float* __restrict__ C2k) {
  float y[TN];
  #pragma unroll
  for (int j = 0; j < TN; ++j) {
    float s = 0.f;
    #pragma unroll
    for (int l = 0; l < TN; ++l) s += Trow[l] * C2k[l * TN + j];  // C2k uniform -> s_load
    y[j] = s;
  }
  uint32_t* pr = Yk + (size_t)r * 8;
  *(uint4*)pr = make_uint4(pk(y[0], y[1]), pk(y[2], y[3]), pk(y[4], y[5]), pk(y[6], y[7]));
  *(uint2*)(pr + 4) = make_uint2(pk(y[8], y[9]), 0u);
}

// ---------- setup kernels ----------
__global__ void k_init(const float* __restrict__ F2, char* __restrict__ ws) {
  int g = blockIdx.x * 256 + threadIdx.x;
  int* deg = (int*)(ws + OFF_DEG);
  int* zr = (int*)(ws + OFF_BAR);
  float* ffs = (float*)(ws + OFF_FFS);
  if (g < NN) deg[g] = 0;
  else if (g < NN + ZERO_INTS) zr[g - NN] = 0;
  else if (g < NN + ZERO_INTS + NT * TN) {
    int pr = g - (NN + ZERO_INTS);
    int k = pr / TN, j = pr % TN;
    const float* F = F2 + (size_t)(k * TN + j) * NF;
    float s = 0.f;
    for (int d = 0; d < NF; ++d) s += F[d] * F[d];
    ffs[k * 16 + j] = s;
  }
}
__global__ void k_deg(const int* __restrict__ ei, int* __restrict__ deg) {
  int e = blockIdx.x * 256 + threadIdx.x;
  if (e < NE) atomicAdd(&deg[ei[e]], 1);
}
__global__ void k_scan(const int* __restrict__ deg, int* __restrict__ rowptr, int* __restrict__ cur) {
  __shared__ int scr[1024];
  int tid = threadIdx.x;
  int loc[5], s = 0;
  #pragma unroll
  for (int r = 0; r < 5; ++r) {
    int idx = tid * 5 + r;
    int d = (idx < NN) ? deg[idx] : 0;
    loc[r] = s; s += d;
  }
  scr[tid] = s; __syncthreads();
  for (int off = 1; off < 1024; off <<= 1) {
    int v = scr[tid];
    int u = (tid >= off) ? scr[tid - off] : 0;
    __syncthreads();
    scr[tid] = v + u;
    __syncthreads();
  }
  int base = (tid > 0) ? scr[tid - 1] : 0;
  #pragma unroll
  for (int r = 0; r < 5; ++r) {
    int idx = tid * 5 + r;
    if (idx < NN) { int v = base + loc[r]; rowptr[idx] = v; cur[idx] = v; }
  }
  if (tid == 1023) rowptr[NN] = scr[1023];
}
__global__ void k_fill(const int* __restrict__ ei, int* __restrict__ cur, int* __restrict__ col) {
  int e = blockIdx.x * 256 + threadIdx.x;
  if (e < NE) {
    int s = ei[e];
    int pos = atomicAdd(&cur[s], 1);
    col[pos] = ei[NE + e];
  }
}

// ---------- main kernel: 16 blocks per template, custom per-template barrier ----------
__global__ __launch_bounds__(TPB, 2) void fgw_main(
    const float* __restrict__ x, const int* __restrict__ rowptr, const int* __restrict__ colidx,
    const float* __restrict__ C2g, const float* __restrict__ F2,
    const float* __restrict__ q0, const float* __restrict__ alpha0,
    const float* __restrict__ ffsg, uint32_t* __restrict__ Yg,
    unsigned* __restrict__ barg, float* __restrict__ sabsg, float* __restrict__ dotsg,
    float* __restrict__ fing, float* __restrict__ csg, float* __restrict__ out) {
  const int bid = blockIdx.x;
  const int k = bid >> 4, b = bid & (NBT - 1);
  const int tid = threadIdx.x;
  const int r0 = b * RPB;
  const int rEnd = min(NN, r0 + RPB);
  const float p = 1.f / NN;
  const float* C2k = C2g + k * 100;
  const float* Fk = F2 + (size_t)k * TN * NF;
  uint32_t* Yk = Yg + (size_t)k * NN * 8;
  unsigned* ctr = barg + k * 16;

  // qv = softmax(q0[k]) (redundant per thread)
  float qv[TN];
  {
    float mx = -1e30f;
    #pragma unroll
    for (int j = 0; j < TN; ++j) mx = fmaxf(mx, q0[k * TN + j]);
    float s = 0.f;
    #pragma unroll
    for (int j = 0; j < TN; ++j) { qv[j] = __expf(q0[k * TN + j] - mx); s += qv[j]; }
    float inv = 1.f / s;
    #pragma unroll
    for (int j = 0; j < TN; ++j) qv[j] *= inv;
  }
  const float alpha = 1.f / (1.f + __expf(-alpha0[0]));
  const float oma = 1.f - alpha;
  float c2q[TN];
  #pragma unroll
  for (int j = 0; j < TN; ++j) {
    float s = 0.f;
    #pragma unroll
    for (int l = 0; l < TN; ++l) { float c = C2k[j * TN + l]; s += c * c * qv[l]; }
    c2q[j] = s;
  }

  // row assignment: strided, up to 2 rows/thread
  int rr[2]; bool vld[2]; int e0[2], e1[2]; float ccr[2];
  rr[0] = r0 + tid; rr[1] = r0 + tid + TPB;
  #pragma unroll
  for (int m = 0; m < 2; ++m) {
    vld[m] = rr[m] < rEnd;
    if (vld[m]) { e0[m] = rowptr[rr[m]]; e1[m] = rowptr[rr[m] + 1]; ccr[m] = (float)(e1[m] - e0[m]) * p; }
    else { e0[m] = 0; e1[m] = 0; ccr[m] = 0.f; }
  }

  // P0: M rows straight into registers
  float Mr[2][TN];
  #pragma unroll
  for (int m = 0; m < 2; ++m) {
    if (vld[m]) {
      const float4* xr = (const float4*)(x + (size_t)rr[m] * NF);
      float acc[TN];
      #pragma unroll
      for (int j = 0; j < TN; ++j) acc[j] = 0.f;
      float xsq = 0.f;
      for (int dc = 0; dc < NF / 4; ++dc) {
        float4 xv = xr[dc];
        xsq += xv.x * xv.x + xv.y * xv.y + xv.z * xv.z + xv.w * xv.w;
        #pragma unroll
        for (int j = 0; j < TN; ++j) {
          const float* Fj = Fk + j * NF + dc * 4;  // uniform -> scalar loads
          acc[j] += xv.x * Fj[0] + xv.y * Fj[1] + xv.z * Fj[2] + xv.w * Fj[3];
        }
      }
      #pragma unroll
      for (int j = 0; j < TN; ++j) Mr[m][j] = xsq + ffsg[k * 16 + j] - 2.f * acc[j];
    }
  }

  float Tr[2][TN], Er[2][TN], Ar[2][TN];
  float gamma = 0.f;
  int barno = 0;

  for (int t = 0; t <= NFW; ++t) {
    // ---- P1: T update (regs) + Y = T@C2 (bf16) to global ----
    #pragma unroll
    for (int m = 0; m < 2; ++m)
      #pragma unroll
      for (int j = 0; j < TN; ++j)
        Tr[m][j] = (t == 0) ? p * qv[j] : Tr[m][j] + gamma * Er[m][j];  // Er holds dT
    #pragma unroll
    for (int m = 0; m < 2; ++m)
      if (vld[m]) ybuild_g(Yk, rr[m], Tr[m], C2k);
    tbar(ctr, (unsigned)(++barno) * NBT);

    if (t < NFW) {
      // ---- P2: gather ATC, G into Er, per-row min shift, |G| sum ----
      float sabs = 0.f, rmn[2];
      #pragma unroll
      for (int m = 0; m < 2; ++m) {
        rmn[m] = 0.f;
        if (vld[m]) {
          float atc[TN];
          #pragma unroll
          for (int j = 0; j < TN; ++j) atc[j] = 0.f;
          gatherG(Yk, colidx, e0[m], e1[m], atc);
          float mn = 1e30f;
          #pragma unroll
          for (int j = 0; j < TN; ++j) {
            float G = oma * Mr[m][j] + 2.f * alpha * (ccr[m] + c2q[j] - 2.f * atc[j]);
            Er[m][j] = G; Ar[m][j] = atc[j];
            sabs += fabsf(G); mn = fminf(mn, G);
          }
          rmn[m] = mn;
        }
      }
      wred_atomic(sabs, sabsg + t * NT + k);
      tbar(ctr, (unsigned)(++barno) * NBT);
      const float reg = 0.05f * aload(sabsg + t * NT + k) * (1.f / (float)(NN * TN)) + 1e-9f;
      const float invreg = 1.f / reg;

      // ---- P3: E = exp(-(G - rowmin)/reg); row shift absorbed exactly by u ----
      #pragma unroll
      for (int m = 0; m < 2; ++m)
        if (vld[m]) {
          #pragma unroll
          for (int j = 0; j < TN; ++j) Er[m][j] = __expf(-(Er[m][j] - rmn[m]) * invreg);
        }

      // ---- P4: Sinkhorn, E in registers, cross-block cs via atomics ----
      float wl[TN], wp[TN];
      #pragma unroll
      for (int j = 0; j < TN; ++j) wl[j] = 1.f;
      for (int it = 0; it < NSK; ++it) {
        float csl[TN];
        #pragma unroll
        for (int j = 0; j < TN; ++j) csl[j] = 0.f;
        #pragma unroll
        for (int m = 0; m < 2; ++m) {
          if (vld[m]) {
            float dot = 0.f;
            #pragma unroll
            for (int j = 0; j < TN; ++j) dot += Er[m][j] * wl[j];
            float u = p / fmaxf(dot, 1e-35f);
            #pragma unroll
            for (int j = 0; j < TN; ++j) csl[j] += Er[m][j] * u;
          }
        }
        float* cs_it = csg + (size_t)((t * NSK + it) * NT + k) * 16;
        #pragma unroll
        for (int j = 0; j < TN; ++j) wred_atomic(csl[j], cs_it + j);
        tbar(ctr, (unsigned)(++barno) * NBT);
        #pragma unroll
        for (int j = 0; j < TN; ++j) {
          wp[j] = wl[j];
          wl[j] = qv[j] / fmaxf(aload(cs_it + j), 1e-35f);
        }
      }

      // ---- P5: dT into Er, b-dots ----
      float bM = 0.f, bC = 0.f, bA = 0.f;
      #pragma unroll
      for (int m = 0; m < 2; ++m) {
        if (vld[m]) {
          float dot = 0.f;
          #pragma unroll
          for (int j = 0; j < TN; ++j) dot += Er[m][j] * wp[j];
          float u = p / fmaxf(dot, 1e-35f);
          #pragma unroll
          for (int j = 0; j < TN; ++j) {
            float d = u * Er[m][j] * wl[j] - Tr[m][j];
            Er[m][j] = d;
            bM += Mr[m][j] * d;
            bC += (ccr[m] + c2q[j]) * d;
            bA += Ar[m][j] * d;
          }
        }
      }
      float* dk = dotsg + (size_t)(t * NT + k) * 4;
      wred_atomic(bM, dk + 0); wred_atomic(bC, dk + 1); wred_atomic(bA, dk + 2);

      // ---- P6: Y2 = dT@C2 to global (same barrier covers b-dots) ----
      #pragma unroll
      for (int m = 0; m < 2; ++m)
        if (vld[m]) ybuild_g(Yk, rr[m], Er[m], C2k);
      tbar(ctr, (unsigned)(++barno) * NBT);

      // ---- P7: a-dot + exact line search ----
      float aacc = 0.f;
      #pragma unroll
      for (int m = 0; m < 2; ++m) {
        if (vld[m]) {
          float ad[TN];
          #pragma unroll
          for (int j = 0; j < TN; ++j) ad[j] = 0.f;
          gatherG(Yk, colidx, e0[m], e1[m], ad);
          #pragma unroll
          for (int j = 0; j < TN; ++j) aacc += ad[j] * Er[m][j];
        }
      }
      wred_atomic(aacc, dk + 3);
      tbar(ctr, (unsigned)(++barno) * NBT);
      float vbM = aload(dk + 0), vbC = aload(dk + 1), vbA = aload(dk + 2), vaA = aload(dk + 3);
      float a_ = -2.f * alpha * vaA;
      float b_ = oma * vbM + alpha * (vbC - 4.f * vbA);
      if (a_ > 0.f) gamma = fminf(fmaxf(-b_ / (2.f * a_ + 1e-16f), 0.f), 1.f);
      else gamma = (a_ + b_ < 0.f) ? 1.f : 0.f;
    } else {
      // ---- final distance ----
      float d1 = 0.f, d2 = 0.f, d3 = 0.f;
      #pragma unroll
      for (int m = 0; m < 2; ++m) {
        if (vld[m]) {
          float atc[TN];
          #pragma unroll
          for (int j = 0; j < TN; ++j) atc[j] = 0.f;
          gatherG(Yk, colidx, e0[m], e1[m], atc);
          #pragma unroll
          for (int j = 0; j < TN; ++j) {
            float Tv = Tr[m][j];
            d1 += Mr[m][j] * Tv;
            d2 += (ccr[m] + c2q[j]) * Tv;
            d3 += atc[j] * Tv;
          }
        }
      }
      float* fk = fing + k * 4;
      wred_atomic(d1, fk + 0); wred_atomic(d2, fk + 1); wred_atomic(d3, fk + 2);
      tbar(ctr, (unsigned)(++barno) * NBT);
      if (b == 0 && tid == 0)
        out[k] = oma * aload(fk + 0) + alpha * (aload(fk + 1) - 2.f * aload(fk + 2));
    }
  }
}

extern "C" void kernel_launch(void* const* d_in, const int* in_sizes, int n_in,
                              void* d_out, int out_size, void* d_ws, size_t ws_size,
                              hipStream_t stream) {
  const float* x  = (const float*)d_in[0];
  const int*   ei = (const int*)d_in[1];
  const float* C2 = (const float*)d_in[2];
  const float* F2 = (const float*)d_in[3];
  const float* q0 = (const float*)d_in[4];
  const float* a0 = (const float*)d_in[5];
  float* out = (float*)d_out;

  char* ws = (char*)d_ws;
  int* deg    = (int*)(ws + OFF_DEG);
  int* rowptr = (int*)(ws + OFF_RP);
  int* cur    = (int*)(ws + OFF_CUR);
  int* col    = (int*)(ws + OFF_COL);
  float* ffs  = (float*)(ws + OFF_FFS);
  unsigned* bar = (unsigned*)(ws + OFF_BAR);
  float* sabs = (float*)(ws + OFF_SABS);
  float* dots = (float*)(ws + OFF_DOTS);
  float* fin  = (float*)(ws + OFF_FIN);
  float* cs   = (float*)(ws + OFF_CS);
  uint32_t* Y = (uint32_t*)(ws + OFF_Y);

  int initN = NN + ZERO_INTS + NT * TN;
  k_init<<<(initN + 255) / 256, 256, 0, stream>>>(F2, ws);
  k_deg<<<(NE + 255) / 256, 256, 0, stream>>>(ei, deg);
  k_scan<<<1, 1024, 0, stream>>>(deg, rowptr, cur);
  k_fill<<<(NE + 255) / 256, 256, 0, stream>>>(ei, cur, col);
  fgw_main<<<NBLK, TPB, 0, stream>>>(x, rowptr, col, C2, F2, q0, a0, ffs, Y,
                                     bar, sabs, dots, fin, cs, out);
}

// Round 3
// 557.943 us; speedup vs baseline: 4.1773x; 4.1773x over previous
//
#include <hip/hip_runtime.h>
#include <stdint.h>

typedef float    f32x4 __attribute__((ext_vector_type(4)));
typedef uint32_t u32x4 __attribute__((ext_vector_type(4)));

#define NN 5000
#define NE 80000
#define NF 128
#define NT 16
#define TN 10
#define NFW 3
#define NSK 10
#define TPB 512
#define NBT 16               // blocks per template
#define RPB 313              // ceil(NN/NBT)
#define NBLK (NT * NBT)      // 256 blocks
#define NSL 10               // redundant-E slots per thread (10*512 >= 5000)
#define PW (1.0f / NN)

// ---------- workspace layout (bytes) ----------
#define OFF_DEG   0u
#define OFF_RP    20224u
#define OFF_CUR   40448u
#define OFF_COL   60672u     // 320000 -> 380672
#define OFF_FFS   380672u    // NT*16 f32 -> 381696
#define OFF_BAR   381696u    // NT*16 u32 -> 382720
#define OFF_SABS  382720u    // 64 f32 -> 382976
#define OFF_DOTS  382976u    // NFW*NT*4 f32 -> 383744
#define OFF_FIN   383744u    // NT*4 f32 -> 384000
#define OFF_Y     384000u    // NT * YSTRIDE
#define YSTRIDE   100096u    // bytes per template Y (25024 u32)
#define OFF_G     1985536u   // NT*NN*48 = 3,840,000 -> 5,825,536
#define ZERO_INTS 576

// ---------- LDS layout (bytes) ----------
#define L_YM   0        // [NN][4] u32 (cols 0-7 bf16)  = 80000
#define L_YT   80000    // [NN] u32 (cols 8-9 bf16)     = 20000 (pad to 100032 for exchange)
#define L_RED  100032   // [8][16] f32 = 512
#define L_CSB  100544   // [16] f32
#define L_UNI  100608   // qv[16], c2q[16] f32 = 128
#define L_COLC 100736   // u16[CCAP]
#define CCAP   24576
#define SMEM_BYTES 149888
#define YCHUNKS 1563    // ceil(100000/64) ; writes up to byte 100032 (pad ok)

// ---------- bf16 helpers ----------
__device__ __forceinline__ uint32_t bfb(float x) {
  uint32_t u = __float_as_uint(x);
  return (u + 0x7fffu + ((u >> 16) & 1u)) >> 16;
}
__device__ __forceinline__ uint32_t pk(float a, float b) { return bfb(a) | (bfb(b) << 16); }
__device__ __forceinline__ float ubl(uint32_t u) { return __uint_as_float(u << 16); }
__device__ __forceinline__ float ubh(uint32_t u) { return __uint_as_float(u & 0xffff0000u); }

// ---------- L2-bypass (IF-coherent) memory ops ----------
__device__ __forceinline__ void st_byp16(void* p, u32x4 v) {
  asm volatile("global_store_dwordx4 %0, %1, off sc0 sc1" :: "v"(p), "v"(v) : "memory");
}
__device__ __forceinline__ void st_byp4(void* p, uint32_t v) {
  asm volatile("global_store_dword %0, %1, off sc0 sc1" :: "v"(p), "v"(v) : "memory");
}
__device__ __forceinline__ void st_byp48(void* p, f32x4 a, f32x4 b, f32x4 c) {
  asm volatile("global_store_dwordx4 %0, %1, off sc0 sc1\n\t"
               "global_store_dwordx4 %0, %2, off offset:16 sc0 sc1\n\t"
               "global_store_dwordx4 %0, %3, off offset:32 sc0 sc1"
               :: "v"(p), "v"(a), "v"(b), "v"(c) : "memory");
}
__device__ __forceinline__ void ld_byp64(const void* p, u32x4& a, u32x4& b, u32x4& c, u32x4& d) {
  asm volatile("global_load_dwordx4 %0, %4, off sc0 sc1\n\t"
               "global_load_dwordx4 %1, %4, off offset:16 sc0 sc1\n\t"
               "global_load_dwordx4 %2, %4, off offset:32 sc0 sc1\n\t"
               "global_load_dwordx4 %3, %4, off offset:48 sc0 sc1\n\t"
               "s_waitcnt vmcnt(0)"
               : "=&v"(a), "=&v"(b), "=&v"(c), "=&v"(d) : "v"(p) : "memory");
}
__device__ __forceinline__ void ld_byp48(const void* p, f32x4& a, f32x4& b, f32x4& c) {
  asm volatile("global_load_dwordx4 %0, %3, off sc0 sc1\n\t"
               "global_load_dwordx4 %1, %3, off offset:16 sc0 sc1\n\t"
               "global_load_dwordx4 %2, %3, off offset:32 sc0 sc1\n\t"
               "s_waitcnt vmcnt(0)"
               : "=&v"(a), "=&v"(b), "=&v"(c) : "v"(p) : "memory");
}
__device__ __forceinline__ void ld_byp48x2(const void* p0, const void* p1,
    f32x4& a0, f32x4& b0, f32x4& c0, f32x4& a1, f32x4& b1, f32x4& c1) {
  asm volatile("global_load_dwordx4 %0, %6, off sc0 sc1\n\t"
               "global_load_dwordx4 %1, %6, off offset:16 sc0 sc1\n\t"
               "global_load_dwordx4 %2, %6, off offset:32 sc0 sc1\n\t"
               "global_load_dwordx4 %3, %7, off sc0 sc1\n\t"
               "global_load_dwordx4 %4, %7, off offset:16 sc0 sc1\n\t"
               "global_load_dwordx4 %5, %7, off offset:32 sc0 sc1\n\t"
               "s_waitcnt vmcnt(0)"
               : "=&v"(a0), "=&v"(b0), "=&v"(c0), "=&v"(a1), "=&v"(b1), "=&v"(c1)
               : "v"(p0), "v"(p1) : "memory");
}

__device__ __forceinline__ float ga_readf(float* p) {
  return __hip_atomic_fetch_add(p, 0.0f, __ATOMIC_RELAXED, __HIP_MEMORY_SCOPE_AGENT);
}

// per-template spin barrier: relaxed RMW at IF, NO cache maintenance.
// each wave drains its own vm ops (bypass stores/atomics ack at IF) first.
__device__ __forceinline__ void tbar(unsigned* ctr, unsigned target) {
  asm volatile("s_waitcnt vmcnt(0)" ::: "memory");
  __syncthreads();
  if (threadIdx.x == 0) {
    __hip_atomic_fetch_add(ctr, 1u, __ATOMIC_RELAXED, __HIP_MEMORY_SCOPE_AGENT);
    while (__hip_atomic_fetch_add(ctr, 0u, __ATOMIC_RELAXED, __HIP_MEMORY_SCOPE_AGENT) < target)
      __builtin_amdgcn_s_sleep(8);
  }
  __syncthreads();
}

// wave-reduce then one IF atomic per wave
__device__ __forceinline__ void wred_atomic(float v, float* gaddr) {
  #pragma unroll
  for (int o = 32; o; o >>= 1) v += __shfl_xor(v, o, 64);
  if ((threadIdx.x & 63) == 0) atomicAdd(gaddr, v);
}

// ---------- setup kernels ----------
__global__ void k_init(const float* __restrict__ F2, char* __restrict__ ws) {
  int g = blockIdx.x * 256 + threadIdx.x;
  if (g < NN) ((int*)(ws + OFF_DEG))[g] = 0;
  int z = g - NN;
  if (z >= 0 && z < ZERO_INTS)
    __hip_atomic_store((unsigned*)(ws + OFF_BAR) + z, 0u, __ATOMIC_RELAXED, __HIP_MEMORY_SCOPE_AGENT);
  int f = g - (NN + ZERO_INTS);
  if (f >= 0 && f < NT * TN) {
    int k = f / TN, j = f % TN;
    const float* F = F2 + (size_t)(k * TN + j) * NF;
    float s = 0.f;
    for (int d = 0; d < NF; ++d) s += F[d] * F[d];
    ((float*)(ws + OFF_FFS))[k * 16 + j] = s;
  }
}
__global__ void k_deg(const int* __restrict__ ei, int* __restrict__ deg) {
  int e = blockIdx.x * 256 + threadIdx.x;
  if (e < NE) atomicAdd(&deg[ei[e]], 1);
}
__global__ void k_scan(const int* __restrict__ deg, int* __restrict__ rowptr, int* __restrict__ cur) {
  __shared__ int scr[1024];
  int tid = threadIdx.x;
  int loc[5], s = 0;
  #pragma unroll
  for (int r = 0; r < 5; ++r) {
    int idx = tid * 5 + r;
    int d = (idx < NN) ? deg[idx] : 0;
    loc[r] = s; s += d;
  }
  scr[tid] = s; __syncthreads();
  for (int off = 1; off < 1024; off <<= 1) {
    int v = scr[tid];
    int u = (tid >= off) ? scr[tid - off] : 0;
    __syncthreads();
    scr[tid] = v + u;
    __syncthreads();
  }
  int base = (tid > 0) ? scr[tid - 1] : 0;
  #pragma unroll
  for (int r = 0; r < 5; ++r) {
    int idx = tid * 5 + r;
    if (idx < NN) { int v = base + loc[r]; rowptr[idx] = v; cur[idx] = v; }
  }
  if (tid == 1023) rowptr[NN] = scr[1023];
}
__global__ void k_fill(const int* __restrict__ ei, int* __restrict__ cur, int* __restrict__ col) {
  int e = blockIdx.x * 256 + threadIdx.x;
  if (e < NE) {
    int s = ei[e];
    int pos = atomicAdd(&cur[s], 1);
    col[pos] = ei[NE + e];
  }
}

// ---------- main kernel ----------
__global__ __launch_bounds__(TPB, 2) void fgw_main(
    const float* __restrict__ x, const int* __restrict__ rowptr, const int* __restrict__ colidx,
    const float* __restrict__ C2g, const float* __restrict__ F2,
    const float* __restrict__ q0, const float* __restrict__ alpha0,
    const float* __restrict__ ffsg, uint32_t* __restrict__ Yg, float* __restrict__ Gg,
    unsigned* __restrict__ barg, float* __restrict__ sabsg, float* __restrict__ dotsg,
    float* __restrict__ fing, float* __restrict__ out) {
  extern __shared__ char smem[];
  float* red  = (float*)(smem + L_RED);
  float* csb  = (float*)(smem + L_CSB);
  float* qvs  = (float*)(smem + L_UNI);
  float* c2qs = (float*)(smem + L_UNI + 64);
  uint16_t* colc = (uint16_t*)(smem + L_COLC);

  const int bid = blockIdx.x;
  const int k = bid >> 4, b = bid & (NBT - 1);
  const int tid = threadIdx.x;
  const int r0 = b * RPB;
  const int rEnd = min(NN, r0 + RPB);
  const int rcnt = rEnd - r0;
  const float* C2k = C2g + k * 100;
  const float* Fk = F2 + (size_t)k * TN * NF;
  uint32_t* Ygk = Yg + (size_t)k * (YSTRIDE / 4);
  float* Gk = Gg + (size_t)k * NN * 12;
  unsigned* ctr = barg + k * 16;

  // ---- P0: uniforms into LDS ----
  if (tid < TN) {
    float mx = -1e30f;
    #pragma unroll
    for (int j = 0; j < TN; ++j) mx = fmaxf(mx, q0[k * TN + j]);
    float s = 0.f;
    #pragma unroll
    for (int j = 0; j < TN; ++j) s += __expf(q0[k * TN + j] - mx);
    qvs[tid] = __expf(q0[k * TN + tid] - mx) / s;
  }
  __syncthreads();
  if (tid < TN) {
    float s = 0.f;
    #pragma unroll
    for (int l = 0; l < TN; ++l) { float c = C2k[tid * TN + l]; s += c * c * qvs[l]; }
    c2qs[tid] = s;
  }
  const float alpha = 1.f / (1.f + __expf(-alpha0[0]));
  const float oma = 1.f - alpha;

  // edge cache (u16 col ids for this block's row range)
  const int eBase = rowptr[r0];
  const int EB = rowptr[rEnd] - eBase;
  const bool usec = EB <= CCAP;
  if (usec)
    for (int e = tid; e < EB; e += TPB) colc[e] = (uint16_t)colidx[eBase + e];

  const bool own = tid < rcnt;
  const int r = r0 + tid;
  int le0 = 0, le1 = 0; float cc = 0.f;
  if (own) {
    le0 = rowptr[r] - eBase; le1 = rowptr[r + 1] - eBase;
    cc = (float)(le1 - le0) * PW;
  }

  // M row in registers
  float Mr[TN];
  if (own) {
    const f32x4* xr = (const f32x4*)(x + (size_t)r * NF);
    float acc[TN];
    #pragma unroll
    for (int j = 0; j < TN; ++j) acc[j] = 0.f;
    float xsq = 0.f;
    for (int dc = 0; dc < NF / 4; ++dc) {
      f32x4 xv = xr[dc];
      xsq += xv[0] * xv[0] + xv[1] * xv[1] + xv[2] * xv[2] + xv[3] * xv[3];
      #pragma unroll
      for (int j = 0; j < TN; ++j) {
        const float* Fj = Fk + j * NF + dc * 4;  // uniform -> scalar loads
        acc[j] += xv[0] * Fj[0] + xv[1] * Fj[1] + xv[2] * Fj[2] + xv[3] * Fj[3];
      }
    }
    #pragma unroll
    for (int j = 0; j < TN; ++j) Mr[j] = xsq + ffsg[k * 16 + j] - 2.f * acc[j];
  }
  __syncthreads();  // qvs/c2qs/colc ready

  float Tr[TN], Er[TN], Ar[TN];  // Er doubles as dT after P5
  float regb[NSL][TN];           // full E (redundant per block)
  float gamma = 0.f, rmno = 0.f;
  unsigned barno = 0;

  for (int t = 0; t <= NFW; ++t) {
    // ---- P1: T update + own-row Y=T@C2 (bf16, bypass write) ----
    if (own) {
      #pragma unroll
      for (int j = 0; j < TN; ++j)
        Tr[j] = (t == 0) ? PW * qvs[j] : Tr[j] + gamma * Er[j];
      float y[TN];
      #pragma unroll
      for (int j = 0; j < TN; ++j) {
        float s = 0.f;
        #pragma unroll
        for (int l = 0; l < TN; ++l) s += Tr[l] * C2k[l * TN + j];
        y[j] = s;
      }
      u32x4 m = { pk(y[0], y[1]), pk(y[2], y[3]), pk(y[4], y[5]), pk(y[6], y[7]) };
      st_byp16(Ygk + (size_t)r * 4, m);
      st_byp4(Ygk + 20000 + r, pk(y[8], y[9]));
    }
    tbar(ctr, (++barno) * NBT);

    // ---- Y exchange: all 100KB -> LDS ----
    {
      const char* src = (const char*)Ygk;
      #pragma unroll
      for (int c = 0; c < 4; ++c) {
        int chunk = tid + c * TPB;
        if (chunk < YCHUNKS) {
          u32x4 a, bb, ccv, d;
          ld_byp64(src + (size_t)chunk * 64, a, bb, ccv, d);
          char* dst = smem + (size_t)chunk * 64;
          *(u32x4*)dst = a; *(u32x4*)(dst + 16) = bb;
          *(u32x4*)(dst + 32) = ccv; *(u32x4*)(dst + 48) = d;
        }
      }
    }
    __syncthreads();

    if (t < NFW) {
      // ---- P2: gather ATC (LDS), G row, sabs, bypass-write G ----
      float sabs = 0.f;
      if (own) {
        float atc[TN];
        #pragma unroll
        for (int j = 0; j < TN; ++j) atc[j] = 0.f;
        for (int e = le0; e < le1; ++e) {
          int c = usec ? (int)colc[e] : colidx[eBase + e];
          u32x4 A = *(const u32x4*)(smem + L_YM + (size_t)c * 16);
          uint32_t B = *(const uint32_t*)(smem + L_YT + (size_t)c * 4);
          atc[0] += ubl(A[0]); atc[1] += ubh(A[0]); atc[2] += ubl(A[1]); atc[3] += ubh(A[1]);
          atc[4] += ubl(A[2]); atc[5] += ubh(A[2]); atc[6] += ubl(A[3]); atc[7] += ubh(A[3]);
          atc[8] += ubl(B);    atc[9] += ubh(B);
        }
        float Gv[TN], mn = 1e30f;
        #pragma unroll
        for (int j = 0; j < TN; ++j) {
          float G = oma * Mr[j] + 2.f * alpha * (cc + c2qs[j] - 2.f * atc[j]);
          Gv[j] = G; Ar[j] = atc[j]; Er[j] = G;
          sabs += fabsf(G); mn = fminf(mn, G);
        }
        rmno = mn;
        f32x4 ga = { Gv[0], Gv[1], Gv[2], Gv[3] };
        f32x4 gb = { Gv[4], Gv[5], Gv[6], Gv[7] };
        f32x4 gc = { Gv[8], Gv[9], 0.f, 0.f };
        st_byp48(Gk + (size_t)r * 12, ga, gb, gc);
      }
      wred_atomic(sabs, sabsg + t * NT + k);
      tbar(ctr, (++barno) * NBT);

      // ---- read sabs + bulk-read G (all rows, redundant) ----
      if (tid == 0) csb[0] = ga_readf(sabsg + t * NT + k);
      #pragma unroll
      for (int s = 0; s < NSL; s += 2) {
        int i0 = s * TPB + tid, i1 = i0 + TPB;
        f32x4 A0, B0, C0, A1, B1, C1;
        if (i1 < NN) {
          ld_byp48x2(Gk + (size_t)i0 * 12, Gk + (size_t)i1 * 12, A0, B0, C0, A1, B1, C1);
          regb[s][0]=A0[0]; regb[s][1]=A0[1]; regb[s][2]=A0[2]; regb[s][3]=A0[3];
          regb[s][4]=B0[0]; regb[s][5]=B0[1]; regb[s][6]=B0[2]; regb[s][7]=B0[3];
          regb[s][8]=C0[0]; regb[s][9]=C0[1];
          regb[s+1][0]=A1[0]; regb[s+1][1]=A1[1]; regb[s+1][2]=A1[2]; regb[s+1][3]=A1[3];
          regb[s+1][4]=B1[0]; regb[s+1][5]=B1[1]; regb[s+1][6]=B1[2]; regb[s+1][7]=B1[3];
          regb[s+1][8]=C1[0]; regb[s+1][9]=C1[1];
        } else {
          ld_byp48(Gk + (size_t)i0 * 12, A0, B0, C0);
          regb[s][0]=A0[0]; regb[s][1]=A0[1]; regb[s][2]=A0[2]; regb[s][3]=A0[3];
          regb[s][4]=B0[0]; regb[s][5]=B0[1]; regb[s][6]=B0[2]; regb[s][7]=B0[3];
          regb[s][8]=C0[0]; regb[s][9]=C0[1];
          #pragma unroll
          for (int j = 0; j < TN; ++j) regb[s+1][j] = 0.f;
        }
      }
      __syncthreads();
      const float reg = 0.05f * csb[0] * (1.f / (float)(NN * TN)) + 1e-9f;
      const float invreg = 1.f / reg;

      // ---- exp (per-row min shift; shift absorbed exactly by u) ----
      #pragma unroll
      for (int s = 0; s < NSL; ++s) {
        int i = s * TPB + tid;
        if (i < NN) {
          float mn = regb[s][0];
          #pragma unroll
          for (int j = 1; j < TN; ++j) mn = fminf(mn, regb[s][j]);
          #pragma unroll
          for (int j = 0; j < TN; ++j) regb[s][j] = __expf(-(regb[s][j] - mn) * invreg);
        } else {
          #pragma unroll
          for (int j = 0; j < TN; ++j) regb[s][j] = 0.f;
        }
      }
      if (own) {
        #pragma unroll
        for (int j = 0; j < TN; ++j) Er[j] = __expf(-(Er[j] - rmno) * invreg);
      }

      // ---- Sinkhorn: 10 iters, block-local (redundant across blocks) ----
      float wl[TN], wp[TN];
      #pragma unroll
      for (int j = 0; j < TN; ++j) { wl[j] = 1.f; wp[j] = 1.f; }
      for (int it = 0; it < NSK; ++it) {
        float csl[TN];
        #pragma unroll
        for (int j = 0; j < TN; ++j) csl[j] = 0.f;
        #pragma unroll
        for (int s = 0; s < NSL; ++s) {
          float dot = 0.f;
          #pragma unroll
          for (int j = 0; j < TN; ++j) dot += regb[s][j] * wl[j];
          float u = PW * __builtin_amdgcn_rcpf(fmaxf(dot, 1e-35f));
          #pragma unroll
          for (int j = 0; j < TN; ++j) csl[j] += regb[s][j] * u;
        }
        #pragma unroll
        for (int j = 0; j < TN; ++j) {
          float v = csl[j];
          #pragma unroll
          for (int o = 32; o; o >>= 1) v += __shfl_xor(v, o, 64);
          if ((tid & 63) == j) red[(tid >> 6) * 16 + j] = v;
        }
        __syncthreads();
        if (tid < TN) {
          float s = 0.f;
          #pragma unroll
          for (int w = 0; w < TPB / 64; ++w) s += red[w * 16 + tid];
          csb[tid] = s;
        }
        __syncthreads();
        #pragma unroll
        for (int j = 0; j < TN; ++j) {
          wp[j] = wl[j];
          wl[j] = qvs[j] * __builtin_amdgcn_rcpf(fmaxf(csb[j], 1e-35f));
        }
      }

      // ---- P5: dT (into Er), b-dots; P6: own-row Y2=dT@C2 write ----
      float bM = 0.f, bC = 0.f, bA = 0.f;
      if (own) {
        float dot = 0.f;
        #pragma unroll
        for (int j = 0; j < TN; ++j) dot += Er[j] * wp[j];
        float u = PW * __builtin_amdgcn_rcpf(fmaxf(dot, 1e-35f));
        #pragma unroll
        for (int j = 0; j < TN; ++j) {
          float d = u * Er[j] * wl[j] - Tr[j];
          Er[j] = d;
          bM += Mr[j] * d;
          bC += (cc + c2qs[j]) * d;
          bA += Ar[j] * d;
        }
      }
      float* dk = dotsg + (size_t)(t * NT + k) * 4;
      wred_atomic(bM, dk + 0); wred_atomic(bC, dk + 1); wred_atomic(bA, dk + 2);
      if (own) {
        float y[TN];
        #pragma unroll
        for (int j = 0; j < TN; ++j) {
          float s = 0.f;
          #pragma unroll
          for (int l = 0; l < TN; ++l) s += Er[l] * C2k[l * TN + j];
          y[j] = s;
        }
        u32x4 m = { pk(y[0], y[1]), pk(y[2], y[3]), pk(y[4], y[5]), pk(y[6], y[7]) };
        st_byp16(Ygk + (size_t)r * 4, m);
        st_byp4(Ygk + 20000 + r, pk(y[8], y[9]));
      }
      tbar(ctr, (++barno) * NBT);

      // ---- Y2 exchange -> LDS ----
      {
        const char* src = (const char*)Ygk;
        #pragma unroll
        for (int c = 0; c < 4; ++c) {
          int chunk = tid + c * TPB;
          if (chunk < YCHUNKS) {
            u32x4 a, bb, ccv, d;
            ld_byp64(src + (size_t)chunk * 64, a, bb, ccv, d);
            char* dst = smem + (size_t)chunk * 64;
            *(u32x4*)dst = a; *(u32x4*)(dst + 16) = bb;
            *(u32x4*)(dst + 32) = ccv; *(u32x4*)(dst + 48) = d;
          }
        }
      }
      __syncthreads();

      // ---- P7: a-dot gather + exact line search ----
      float aacc = 0.f;
      if (own) {
        float ad[TN];
        #pragma unroll
        for (int j = 0; j < TN; ++j) ad[j] = 0.f;
        for (int e = le0; e < le1; ++e) {
          int c = usec ? (int)colc[e] : colidx[eBase + e];
          u32x4 A = *(const u32x4*)(smem + L_YM + (size_t)c * 16);
          uint32_t B = *(const uint32_t*)(smem + L_YT + (size_t)c * 4);
          ad[0] += ubl(A[0]); ad[1] += ubh(A[0]); ad[2] += ubl(A[1]); ad[3] += ubh(A[1]);
          ad[4] += ubl(A[2]); ad[5] += ubh(A[2]); ad[6] += ubl(A[3]); ad[7] += ubh(A[3]);
          ad[8] += ubl(B);    ad[9] += ubh(B);
        }
        #pragma unroll
        for (int j = 0; j < TN; ++j) aacc += ad[j] * Er[j];
      }
      wred_atomic(aacc, dk + 3);
      tbar(ctr, (++barno) * NBT);
      if (tid < 4) csb[tid] = ga_readf(dk + tid);
      __syncthreads();
      float a_ = -2.f * alpha * csb[3];
      float b_ = oma * csb[0] + alpha * (csb[1] - 4.f * csb[2]);
      if (a_ > 0.f) gamma = fminf(fmaxf(-b_ / (2.f * a_ + 1e-16f), 0.f), 1.f);
      else gamma = (a_ + b_ < 0.f) ? 1.f : 0.f;
      __syncthreads();
    } else {
      // ---- final distance ----
      float d1 = 0.f, d2 = 0.f, d3 = 0.f;
      if (own) {
        float atc[TN];
        #pragma unroll
        for (int j = 0; j < TN; ++j) atc[j] = 0.f;
        for (int e = le0; e < le1; ++e) {
          int c = usec ? (int)colc[e] : colidx[eBase + e];
          u32x4 A = *(const u32x4*)(smem + L_YM + (size_t)c * 16);
          uint32_t B = *(const uint32_t*)(smem + L_YT + (size_t)c * 4);
          atc[0] += ubl(A[0]); atc[1] += ubh(A[0]); atc[2] += ubl(A[1]); atc[3] += ubh(A[1]);
          atc[4] += ubl(A[2]); atc[5] += ubh(A[2]); atc[6] += ubl(A[3]); atc[7] += ubh(A[3]);
          atc[8] += ubl(B);    atc[9] += ubh(B);
        }
        #pragma unroll
        for (int j = 0; j < TN; ++j) {
          float Tv = Tr[j];
          d1 += Mr[j] * Tv;
          d2 += (cc + c2qs[j]) * Tv;
          d3 += atc[j] * Tv;
        }
      }
      float* fk = fing + k * 4;
      wred_atomic(d1, fk + 0); wred_atomic(d2, fk + 1); wred_atomic(d3, fk + 2);
      tbar(ctr, (++barno) * NBT);
      if (b == 0) {
        if (tid < 3) csb[tid] = ga_readf(fk + tid);
        __syncthreads();
        if (tid == 0) out[k] = oma * csb[0] + alpha * (csb[1] - 2.f * csb[2]);
      }
    }
  }
}

extern "C" void kernel_launch(void* const* d_in, const int* in_sizes, int n_in,
                              void* d_out, int out_size, void* d_ws, size_t ws_size,
                              hipStream_t stream) {
  const float* x  = (const float*)d_in[0];
  const int*   ei = (const int*)d_in[1];
  const float* C2 = (const float*)d_in[2];
  const float* F2 = (const float*)d_in[3];
  const float* q0 = (const float*)d_in[4];
  const float* a0 = (const float*)d_in[5];
  float* outp = (float*)d_out;

  char* ws = (char*)d_ws;
  int* deg    = (int*)(ws + OFF_DEG);
  int* rowptr = (int*)(ws + OFF_RP);
  int* cur    = (int*)(ws + OFF_CUR);
  int* col    = (int*)(ws + OFF_COL);
  float* ffs  = (float*)(ws + OFF_FFS);
  unsigned* bar = (unsigned*)(ws + OFF_BAR);
  float* sabs = (float*)(ws + OFF_SABS);
  float* dots = (float*)(ws + OFF_DOTS);
  float* fin  = (float*)(ws + OFF_FIN);
  uint32_t* Y = (uint32_t*)(ws + OFF_Y);
  float* G    = (float*)(ws + OFF_G);

  hipFuncSetAttribute((const void*)fgw_main, hipFuncAttributeMaxDynamicSharedMemorySize, SMEM_BYTES);

  int initN = NN + ZERO_INTS + NT * TN;
  k_init<<<(initN + 255) / 256, 256, 0, stream>>>(F2, ws);
  k_deg<<<(NE + 255) / 256, 256, 0, stream>>>(ei, deg);
  k_scan<<<1, 1024, 0, stream>>>(deg, rowptr, cur);
  k_fill<<<(NE + 255) / 256, 256, 0, stream>>>(ei, cur, col);

  void* args[] = { (void*)&x, (void*)&rowptr, (void*)&col, (void*)&C2, (void*)&F2,
                   (void*)&q0, (void*)&a0, (void*)&ffs, (void*)&Y, (void*)&G,
                   (void*)&bar, (void*)&sabs, (void*)&dots, (void*)&fin, (void*)&outp };
  hipLaunchCooperativeKernel((const void*)fgw_main, dim3(NBLK), dim3(TPB), args,
                             SMEM_BYTES, stream);
}

// Round 5
// 483.630 us; speedup vs baseline: 4.8192x; 1.1537x over previous
//
#include <hip/hip_runtime.h>
#include <stdint.h>

typedef float    f32x4 __attribute__((ext_vector_type(4)));
typedef uint32_t u32x4 __attribute__((ext_vector_type(4)));

#define NN 5000
#define NE 80000
#define NF 128
#define NT 16
#define TN 10
#define NFW 3
#define NSK 10
#define PW (1.0f/5000.0f)
#define RB 128          // threads per row-block
#define GRX 40          // ceil(NN/RB)

// ---------- workspace layout (bytes) ----------
#define OFF_DEG  0u
#define OFF_RP   20224u
#define OFF_CUR  40448u
#define OFF_COL  60672u      // 320000 B
#define OFF_SC   380672u     // 384 f32 scratch (per-template!):
                             //   [t*16+k]          sabs        (t<3)
                             //   [64+(t*16+k)*4+d] dots bM,bC,bA,aA
                             //   [256+k*4+d]       fin d1,d2,d3
                             //   int[320+k]        completion ctr
#define OFF_M    393216u     // 16*5000*48 = 3,840,000
#define OFF_T    4233216u    // 3,840,000
#define OFF_GT   8073216u    // G, overwritten in-place by T_new (kSink)
#define OFF_Y1M  11913216u   // 16*5000*16
#define OFF_Y1T  13193216u   // 16*5000*4
#define OFF_Y2M  13513216u
#define OFF_Y2T  14793216u   // end 15,113,216
#define SC_FLOATS 384

// ---------- helpers ----------
__device__ __forceinline__ uint32_t bfb(float x) {
  uint32_t u = __float_as_uint(x);
  return (u + 0x7fffu + ((u >> 16) & 1u)) >> 16;
}
__device__ __forceinline__ uint32_t pk(float a, float b) { return bfb(a) | (bfb(b) << 16); }
__device__ __forceinline__ float ubl(uint32_t u) { return __uint_as_float(u << 16); }
__device__ __forceinline__ float ubh(uint32_t u) { return __uint_as_float(u & 0xffff0000u); }
__device__ __forceinline__ float sigm(float z) { return 1.f / (1.f + __expf(-z)); }

__device__ __forceinline__ void ld12(const float* p, float* v) {
  f32x4 a = *(const f32x4*)p, b = *(const f32x4*)(p + 4), c = *(const f32x4*)(p + 8);
  v[0]=a[0]; v[1]=a[1]; v[2]=a[2]; v[3]=a[3]; v[4]=b[0]; v[5]=b[1]; v[6]=b[2]; v[7]=b[3];
  v[8]=c[0]; v[9]=c[1];
}
__device__ __forceinline__ void st12(float* p, const float* v) {
  *(f32x4*)p       = (f32x4){v[0], v[1], v[2], v[3]};
  *(f32x4*)(p + 4) = (f32x4){v[4], v[5], v[6], v[7]};
  *(f32x4*)(p + 8) = (f32x4){v[8], v[9], 0.f, 0.f};
}

__device__ __forceinline__ void gath(const u32x4* __restrict__ YM, const uint32_t* __restrict__ YT,
                                     const int* __restrict__ col, int e0, int e1, float* acc) {
  for (int e = e0; e < e1; ++e) {
    int c = col[e];
    u32x4 A = YM[c]; uint32_t B = YT[c];
    acc[0] += ubl(A[0]); acc[1] += ubh(A[0]); acc[2] += ubl(A[1]); acc[3] += ubh(A[1]);
    acc[4] += ubl(A[2]); acc[5] += ubh(A[2]); acc[6] += ubl(A[3]); acc[7] += ubh(A[3]);
    acc[8] += ubl(B);    acc[9] += ubh(B);
  }
}

__device__ __forceinline__ void ywrite(u32x4* __restrict__ YM, uint32_t* __restrict__ YT,
                                       int i, const float* r, const float* __restrict__ C2k) {
  float y[TN];
  #pragma unroll
  for (int j = 0; j < TN; ++j) {
    float s = 0.f;
    #pragma unroll
    for (int l = 0; l < TN; ++l) s += r[l] * C2k[l * TN + j];  // C2k uniform -> scalar loads
    y[j] = s;
  }
  YM[i] = (u32x4){pk(y[0], y[1]), pk(y[2], y[3]), pk(y[4], y[5]), pk(y[6], y[7])};
  YT[i] = pk(y[8], y[9]);
}

// c2q into LDS; one syncthreads
__device__ __forceinline__ void setup_c2q(const float* __restrict__ q0, const float* __restrict__ C2k,
                                          int k, int tid, float* c2qs) {
  if (tid < TN) {
    float mx = -1e30f, e[TN], s = 0.f;
    #pragma unroll
    for (int j = 0; j < TN; ++j) mx = fmaxf(mx, q0[k * TN + j]);
    #pragma unroll
    for (int j = 0; j < TN; ++j) { e[j] = __expf(q0[k * TN + j] - mx); s += e[j]; }
    float inv = 1.f / s;
    float c2 = 0.f;
    #pragma unroll
    for (int l = 0; l < TN; ++l) { float c = C2k[tid * TN + l]; c2 += c * c * e[l] * inv; }
    c2qs[tid] = c2;
  }
  __syncthreads();
}

// ---------- setup kernels ----------
__global__ void k_init(char* __restrict__ ws) {
  int g = blockIdx.x * 256 + threadIdx.x;
  if (g < NN) ((int*)(ws + OFF_DEG))[g] = 0;
  int z = g - NN;
  if (z >= 0 && z < SC_FLOATS) ((float*)(ws + OFF_SC))[z] = 0.f;
}
__global__ void k_deg(const int* __restrict__ ei, int* __restrict__ deg) {
  int e = blockIdx.x * 256 + threadIdx.x;
  if (e < NE) atomicAdd(&deg[ei[e]], 1);
}
__global__ void k_scan(const int* __restrict__ deg, int* __restrict__ rowptr, int* __restrict__ cur) {
  __shared__ int scr[1024];
  int tid = threadIdx.x;
  int loc[5], s = 0;
  #pragma unroll
  for (int r = 0; r < 5; ++r) {
    int idx = tid * 5 + r;
    int d = (idx < NN) ? deg[idx] : 0;
    loc[r] = s; s += d;
  }
  scr[tid] = s; __syncthreads();
  for (int off = 1; off < 1024; off <<= 1) {
    int v = scr[tid];
    int u = (tid >= off) ? scr[tid - off] : 0;
    __syncthreads();
    scr[tid] = v + u;
    __syncthreads();
  }
  int base = (tid > 0) ? scr[tid - 1] : 0;
  #pragma unroll
  for (int r = 0; r < 5; ++r) {
    int idx = tid * 5 + r;
    if (idx < NN) { int v = base + loc[r]; rowptr[idx] = v; cur[idx] = v; }
  }
  if (tid == 1023) rowptr[NN] = scr[1023];
}
__global__ void k_fill(const int* __restrict__ ei, int* __restrict__ cur, int* __restrict__ col) {
  int e = blockIdx.x * 256 + threadIdx.x;
  if (e < NE) {
    int s = ei[e];
    int pos = atomicAdd(&cur[s], 1);
    col[pos] = ei[NE + e];
  }
}

// ---------- M build ----------
__global__ void kM(const float* __restrict__ x, const float* __restrict__ F2,
                   float* __restrict__ Mb) {
  __shared__ float ffs[TN];
  const int k = blockIdx.y, tid = threadIdx.x;
  const int i = blockIdx.x * RB + tid;
  const float* Fk = F2 + (size_t)k * TN * NF;
  if (tid < TN) {
    float s = 0.f;
    for (int d = 0; d < NF; ++d) { float f = Fk[tid * NF + d]; s += f * f; }
    ffs[tid] = s;
  }
  __syncthreads();
  if (i >= NN) return;
  const f32x4* xr = (const f32x4*)(x + (size_t)i * NF);
  float acc[TN];
  #pragma unroll
  for (int j = 0; j < TN; ++j) acc[j] = 0.f;
  float xsq = 0.f;
  for (int dc = 0; dc < NF / 4; ++dc) {
    f32x4 xv = xr[dc];
    xsq += xv[0]*xv[0] + xv[1]*xv[1] + xv[2]*xv[2] + xv[3]*xv[3];
    #pragma unroll
    for (int j = 0; j < TN; ++j) {
      const float* Fj = Fk + j * NF + dc * 4;  // uniform -> scalar loads
      acc[j] += xv[0]*Fj[0] + xv[1]*Fj[1] + xv[2]*Fj[2] + xv[3]*Fj[3];
    }
  }
  float v[TN];
  #pragma unroll
  for (int j = 0; j < TN; ++j) v[j] = xsq + ffs[j] - 2.f * acc[j];
  st12(Mb + ((size_t)k * NN + i) * 12, v);
}

// ---------- kY: T update + Y1 = T@C2 ----------
__global__ void kY(const float* __restrict__ q0, const float* __restrict__ C2,
                   const float* __restrict__ sc, float* __restrict__ Tb,
                   const float* __restrict__ Tn, u32x4* __restrict__ Y1M,
                   uint32_t* __restrict__ Y1T, const float* __restrict__ a0, int t) {
  __shared__ float qvs[16];
  const int k = blockIdx.y, tid = threadIdx.x;
  const int i = blockIdx.x * RB + tid;
  const float* C2k = C2 + k * 100;
  if (tid < TN) {
    float mx = -1e30f, e[TN], s = 0.f;
    #pragma unroll
    for (int j = 0; j < TN; ++j) mx = fmaxf(mx, q0[k * TN + j]);
    #pragma unroll
    for (int j = 0; j < TN; ++j) { e[j] = __expf(q0[k * TN + j] - mx); s += e[j]; }
    qvs[tid] = e[tid] / s;
  }
  __syncthreads();
  if (i >= NN) return;
  float gamma = 0.f;
  if (t > 0) {
    const float alpha = sigm(a0[0]), oma = 1.f - alpha;
    const float* dk = sc + 64 + (size_t)((t - 1) * NT + k) * 4;   // per-(t,k)!
    float a_ = -2.f * alpha * dk[3];
    float b_ = oma * dk[0] + alpha * (dk[1] - 4.f * dk[2]);
    gamma = (a_ > 0.f) ? fminf(fmaxf(-b_ / (2.f * a_ + 1e-16f), 0.f), 1.f)
                       : ((a_ + b_ < 0.f) ? 1.f : 0.f);
  }
  const size_t ro = ((size_t)k * NN + i) * 12;
  float Trow[TN];
  if (t == 0) {
    #pragma unroll
    for (int j = 0; j < TN; ++j) Trow[j] = PW * qvs[j];
  } else {
    float tv[TN], nv[TN];
    ld12(Tb + ro, tv); ld12(Tn + ro, nv);
    #pragma unroll
    for (int j = 0; j < TN; ++j) Trow[j] = tv[j] + gamma * (nv[j] - tv[j]);
  }
  st12(Tb + ro, Trow);
  ywrite(Y1M + (size_t)k * NN, Y1T + (size_t)k * NN, i, Trow, C2k);
}

// ---------- kG: gather ATC, G = oma*M + 2a(cc + c2q - 2atc), sabs ----------
__global__ void kG(const int* __restrict__ rowptr, const int* __restrict__ col,
                   const float* __restrict__ Mb, const u32x4* __restrict__ Y1M,
                   const uint32_t* __restrict__ Y1T, const float* __restrict__ q0,
                   const float* __restrict__ C2, const float* __restrict__ a0,
                   float* __restrict__ Gb, float* __restrict__ sc, int t) {
  __shared__ float c2qs[16];
  __shared__ float redl[2];
  const int k = blockIdx.y, tid = threadIdx.x;
  const int i = blockIdx.x * RB + tid;
  setup_c2q(q0, C2 + k * 100, k, tid, c2qs);
  const float alpha = sigm(a0[0]), oma = 1.f - alpha;
  float sabs = 0.f;
  if (i < NN) {
    int e0 = rowptr[i], e1 = rowptr[i + 1];
    float cc = (float)(e1 - e0) * PW;
    float atc[TN];
    #pragma unroll
    for (int j = 0; j < TN; ++j) atc[j] = 0.f;
    gath(Y1M + (size_t)k * NN, Y1T + (size_t)k * NN, col, e0, e1, atc);
    float mv[TN];
    ld12(Mb + ((size_t)k * NN + i) * 12, mv);
    float Gv[TN];
    #pragma unroll
    for (int j = 0; j < TN; ++j) {
      float G = oma * mv[j] + 2.f * alpha * (cc + c2qs[j] - 2.f * atc[j]);
      Gv[j] = G; sabs += fabsf(G);
    }
    st12(Gb + ((size_t)k * NN + i) * 12, Gv);
  }
  #pragma unroll
  for (int o = 32; o; o >>= 1) sabs += __shfl_xor(sabs, o, 64);
  if ((tid & 63) == 0) redl[tid >> 6] = sabs;
  __syncthreads();
  if (tid == 0) atomicAdd(sc + t * NT + k, redl[0] + redl[1]);   // per-(t,k)!
}

// ---------- kSink: 10 Sinkhorn iters, E in regs, Tn in-place over G ----------
__global__ __launch_bounds__(1024) void kSink(float* __restrict__ Gb,
                                              const float* __restrict__ q0,
                                              const float* __restrict__ sc, int t) {
  __shared__ float red[16 * 16];
  __shared__ float wls[16];
  const int k = blockIdx.x, tid = threadIdx.x;
  const int wid = tid >> 6;
  float qme = 0.f;
  if (tid < TN) {
    float mx = -1e30f, e[TN], s = 0.f;
    #pragma unroll
    for (int j = 0; j < TN; ++j) mx = fmaxf(mx, q0[k * TN + j]);
    #pragma unroll
    for (int j = 0; j < TN; ++j) { e[j] = __expf(q0[k * TN + j] - mx); s += e[j]; }
    qme = e[tid] / s;
  }
  const float reg = 0.05f * sc[t * NT + k] * (1.f / (float)(NN * TN)) + 1e-9f;  // per-(t,k)!
  const float invreg = 1.f / reg;
  float* Gk = Gb + (size_t)k * NN * 12;

  float E[5][TN];
  bool v[5];
  #pragma unroll
  for (int s = 0; s < 5; ++s) {
    int i = s * 1024 + tid;
    v[s] = i < NN;
    if (v[s]) {
      float g[TN];
      ld12(Gk + (size_t)i * 12, g);
      float mn = g[0];
      #pragma unroll
      for (int j = 1; j < TN; ++j) mn = fminf(mn, g[j]);
      #pragma unroll
      for (int j = 0; j < TN; ++j) E[s][j] = __expf(-(g[j] - mn) * invreg);
    } else {
      #pragma unroll
      for (int j = 0; j < TN; ++j) E[s][j] = 0.f;
    }
  }

  float wlr[TN], wpr[TN];
  #pragma unroll
  for (int j = 0; j < TN; ++j) { wlr[j] = 1.f; wpr[j] = 1.f; }
  for (int it = 0; it < NSK; ++it) {
    float csl[TN];
    #pragma unroll
    for (int j = 0; j < TN; ++j) csl[j] = 0.f;
    #pragma unroll
    for (int s = 0; s < 5; ++s) {
      float dot = 0.f;
      #pragma unroll
      for (int j = 0; j < TN; ++j) dot += E[s][j] * wlr[j];
      float u = PW * __builtin_amdgcn_rcpf(fmaxf(dot, 1e-35f));
      #pragma unroll
      for (int j = 0; j < TN; ++j) csl[j] += E[s][j] * u;
    }
    #pragma unroll
    for (int j = 0; j < TN; ++j) {
      float vv = csl[j];
      #pragma unroll
      for (int o = 32; o; o >>= 1) vv += __shfl_xor(vv, o, 64);
      if ((tid & 63) == j) red[wid * 16 + j] = vv;
    }
    __syncthreads();
    if (tid < TN) {
      float s = 0.f;
      #pragma unroll
      for (int w = 0; w < 16; ++w) s += red[w * 16 + tid];
      wls[tid] = qme * __builtin_amdgcn_rcpf(fmaxf(s, 1e-35f));
    }
    __syncthreads();
    #pragma unroll
    for (int j = 0; j < TN; ++j) { wpr[j] = wlr[j]; wlr[j] = wls[j]; }
  }
  // Tn = u(wp) * E * wl, overwrite G rows
  #pragma unroll
  for (int s = 0; s < 5; ++s) {
    if (v[s]) {
      int i = s * 1024 + tid;
      float dot = 0.f;
      #pragma unroll
      for (int j = 0; j < TN; ++j) dot += E[s][j] * wpr[j];
      float u = PW * __builtin_amdgcn_rcpf(fmaxf(dot, 1e-35f));
      float tn[TN];
      #pragma unroll
      for (int j = 0; j < TN; ++j) tn[j] = u * E[s][j] * wlr[j];
      st12(Gk + (size_t)i * 12, tn);
    }
  }
}

// ---------- kDT: dT = Tn - T, bM/bC, Y2 = dT@C2 ----------
__global__ void kDT(const int* __restrict__ rowptr, const float* __restrict__ Mb,
                    const float* __restrict__ Tb, const float* __restrict__ Tn,
                    const float* __restrict__ q0, const float* __restrict__ C2,
                    u32x4* __restrict__ Y2M, uint32_t* __restrict__ Y2T,
                    float* __restrict__ sc, int t) {
  __shared__ float c2qs[16];
  __shared__ float redl[4];
  const int k = blockIdx.y, tid = threadIdx.x;
  const int i = blockIdx.x * RB + tid;
  const float* C2k = C2 + k * 100;
  setup_c2q(q0, C2k, k, tid, c2qs);
  float bM = 0.f, bC = 0.f;
  if (i < NN) {
    const size_t ro = ((size_t)k * NN + i) * 12;
    float tv[TN], nv[TN], mv[TN], d[TN];
    ld12(Tb + ro, tv); ld12(Tn + ro, nv); ld12(Mb + ro, mv);
    float cc = (float)(rowptr[i + 1] - rowptr[i]) * PW;
    #pragma unroll
    for (int j = 0; j < TN; ++j) {
      d[j] = nv[j] - tv[j];
      bM += mv[j] * d[j];
      bC += (cc + c2qs[j]) * d[j];
    }
    ywrite(Y2M + (size_t)k * NN, Y2T + (size_t)k * NN, i, d, C2k);
  }
  #pragma unroll
  for (int o = 32; o; o >>= 1) { bM += __shfl_xor(bM, o, 64); bC += __shfl_xor(bC, o, 64); }
  if ((tid & 63) == 0) { int w = tid >> 6; redl[w * 2] = bM; redl[w * 2 + 1] = bC; }
  __syncthreads();
  if (tid == 0) {
    float* dk = sc + 64 + (size_t)(t * NT + k) * 4;              // per-(t,k)!
    atomicAdd(dk + 0, redl[0] + redl[2]);
    atomicAdd(dk + 1, redl[1] + redl[3]);
  }
}

// ---------- kA: gather Y1 & Y2, bA + a-dot ----------
__global__ void kA(const int* __restrict__ rowptr, const int* __restrict__ col,
                   const float* __restrict__ Tb, const float* __restrict__ Tn,
                   const u32x4* __restrict__ Y1M, const uint32_t* __restrict__ Y1T,
                   const u32x4* __restrict__ Y2M, const uint32_t* __restrict__ Y2T,
                   float* __restrict__ sc, int t) {
  __shared__ float redl[4];
  const int k = blockIdx.y, tid = threadIdx.x;
  const int i = blockIdx.x * RB + tid;
  float bA = 0.f, aacc = 0.f;
  if (i < NN) {
    const size_t ro = ((size_t)k * NN + i) * 12;
    float tv[TN], nv[TN];
    ld12(Tb + ro, tv); ld12(Tn + ro, nv);
    int e0 = rowptr[i], e1 = rowptr[i + 1];
    const u32x4* Y1Mk = Y1M + (size_t)k * NN; const uint32_t* Y1Tk = Y1T + (size_t)k * NN;
    const u32x4* Y2Mk = Y2M + (size_t)k * NN; const uint32_t* Y2Tk = Y2T + (size_t)k * NN;
    float atc[TN], adt[TN];
    #pragma unroll
    for (int j = 0; j < TN; ++j) { atc[j] = 0.f; adt[j] = 0.f; }
    for (int e = e0; e < e1; ++e) {
      int c = col[e];
      u32x4 A1 = Y1Mk[c]; uint32_t B1 = Y1Tk[c];
      u32x4 A2 = Y2Mk[c]; uint32_t B2 = Y2Tk[c];
      atc[0] += ubl(A1[0]); atc[1] += ubh(A1[0]); atc[2] += ubl(A1[1]); atc[3] += ubh(A1[1]);
      atc[4] += ubl(A1[2]); atc[5] += ubh(A1[2]); atc[6] += ubl(A1[3]); atc[7] += ubh(A1[3]);
      atc[8] += ubl(B1);    atc[9] += ubh(B1);
      adt[0] += ubl(A2[0]); adt[1] += ubh(A2[0]); adt[2] += ubl(A2[1]); adt[3] += ubh(A2[1]);
      adt[4] += ubl(A2[2]); adt[5] += ubh(A2[2]); adt[6] += ubl(A2[3]); adt[7] += ubh(A2[3]);
      adt[8] += ubl(B2);    adt[9] += ubh(B2);
    }
    #pragma unroll
    for (int j = 0; j < TN; ++j) {
      float d = nv[j] - tv[j];
      bA += atc[j] * d;
      aacc += adt[j] * d;
    }
  }
  #pragma unroll
  for (int o = 32; o; o >>= 1) { bA += __shfl_xor(bA, o, 64); aacc += __shfl_xor(aacc, o, 64); }
  if ((tid & 63) == 0) { int w = tid >> 6; redl[w * 2] = bA; redl[w * 2 + 1] = aacc; }
  __syncthreads();
  if (tid == 0) {
    float* dk = sc + 64 + (size_t)(t * NT + k) * 4;              // per-(t,k)!
    atomicAdd(dk + 2, redl[0] + redl[2]);
    atomicAdd(dk + 3, redl[1] + redl[3]);
  }
}

// ---------- kFin: distance terms + last-block out write ----------
__global__ void kFin(const int* __restrict__ rowptr, const int* __restrict__ col,
                     const float* __restrict__ Mb, const float* __restrict__ Tb,
                     const u32x4* __restrict__ Y1M, const uint32_t* __restrict__ Y1T,
                     const float* __restrict__ q0, const float* __restrict__ C2,
                     const float* __restrict__ a0, float* __restrict__ sc,
                     float* __restrict__ out) {
  __shared__ float c2qs[16];
  __shared__ float redl[6];
  const int k = blockIdx.y, tid = threadIdx.x;
  const int i = blockIdx.x * RB + tid;
  setup_c2q(q0, C2 + k * 100, k, tid, c2qs);
  const float alpha = sigm(a0[0]), oma = 1.f - alpha;
  float d1 = 0.f, d2 = 0.f, d3 = 0.f;
  if (i < NN) {
    const size_t ro = ((size_t)k * NN + i) * 12;
    float tv[TN], mv[TN];
    ld12(Tb + ro, tv); ld12(Mb + ro, mv);
    int e0 = rowptr[i], e1 = rowptr[i + 1];
    float cc = (float)(e1 - e0) * PW;
    float atc[TN];
    #pragma unroll
    for (int j = 0; j < TN; ++j) atc[j] = 0.f;
    gath(Y1M + (size_t)k * NN, Y1T + (size_t)k * NN, col, e0, e1, atc);
    #pragma unroll
    for (int j = 0; j < TN; ++j) {
      d1 += mv[j] * tv[j];
      d2 += (cc + c2qs[j]) * tv[j];
      d3 += atc[j] * tv[j];
    }
  }
  #pragma unroll
  for (int o = 32; o; o >>= 1) {
    d1 += __shfl_xor(d1, o, 64); d2 += __shfl_xor(d2, o, 64); d3 += __shfl_xor(d3, o, 64);
  }
  if ((tid & 63) == 0) {
    int w = tid >> 6;
    redl[w * 3] = d1; redl[w * 3 + 1] = d2; redl[w * 3 + 2] = d3;
  }
  __syncthreads();
  float* fk = sc + 256 + k * 4;
  if (tid == 0) {
    atomicAdd(fk + 0, redl[0] + redl[3]);
    atomicAdd(fk + 1, redl[1] + redl[4]);
    atomicAdd(fk + 2, redl[2] + redl[5]);
  }
  asm volatile("s_waitcnt vmcnt(0)" ::: "memory");
  __syncthreads();
  if (tid == 0) {
    int* ctr = (int*)sc + 320 + k;
    int old = __hip_atomic_fetch_add(ctr, 1, __ATOMIC_RELAXED, __HIP_MEMORY_SCOPE_AGENT);
    if (old == GRX - 1) {
      float f0 = __hip_atomic_fetch_add(fk + 0, 0.f, __ATOMIC_RELAXED, __HIP_MEMORY_SCOPE_AGENT);
      float f1 = __hip_atomic_fetch_add(fk + 1, 0.f, __ATOMIC_RELAXED, __HIP_MEMORY_SCOPE_AGENT);
      float f2 = __hip_atomic_fetch_add(fk + 2, 0.f, __ATOMIC_RELAXED, __HIP_MEMORY_SCOPE_AGENT);
      out[k] = oma * f0 + alpha * (f1 - 2.f * f2);
    }
  }
}

extern "C" void kernel_launch(void* const* d_in, const int* in_sizes, int n_in,
                              void* d_out, int out_size, void* d_ws, size_t ws_size,
                              hipStream_t stream) {
  const float* x  = (const float*)d_in[0];
  const int*   ei = (const int*)d_in[1];
  const float* C2 = (const float*)d_in[2];
  const float* F2 = (const float*)d_in[3];
  const float* q0 = (const float*)d_in[4];
  const float* a0 = (const float*)d_in[5];
  float* out = (float*)d_out;

  char* ws = (char*)d_ws;
  int* deg    = (int*)(ws + OFF_DEG);
  int* rowptr = (int*)(ws + OFF_RP);
  int* cur    = (int*)(ws + OFF_CUR);
  int* col    = (int*)(ws + OFF_COL);
  float* sc   = (float*)(ws + OFF_SC);
  float* Mb   = (float*)(ws + OFF_M);
  float* Tb   = (float*)(ws + OFF_T);
  float* Gt   = (float*)(ws + OFF_GT);
  u32x4* Y1M  = (u32x4*)(ws + OFF_Y1M);
  uint32_t* Y1T = (uint32_t*)(ws + OFF_Y1T);
  u32x4* Y2M  = (u32x4*)(ws + OFF_Y2M);
  uint32_t* Y2T = (uint32_t*)(ws + OFF_Y2T);

  const dim3 rg(GRX, NT), rb(RB);

  k_init<<<(NN + SC_FLOATS + 255) / 256, 256, 0, stream>>>(ws);
  k_deg<<<(NE + 255) / 256, 256, 0, stream>>>(ei, deg);
  k_scan<<<1, 1024, 0, stream>>>(deg, rowptr, cur);
  k_fill<<<(NE + 255) / 256, 256, 0, stream>>>(ei, cur, col);
  kM<<<rg, rb, 0, stream>>>(x, F2, Mb);

  for (int t = 0; t < NFW; ++t) {
    kY<<<rg, rb, 0, stream>>>(q0, C2, sc, Tb, Gt, Y1M, Y1T, a0, t);
    kG<<<rg, rb, 0, stream>>>(rowptr, col, Mb, Y1M, Y1T, q0, C2, a0, Gt, sc, t);
    kSink<<<NT, 1024, 0, stream>>>(Gt, q0, sc, t);
    kDT<<<rg, rb, 0, stream>>>(rowptr, Mb, Tb, Gt, q0, C2, Y2M, Y2T, sc, t);
    kA<<<rg, rb, 0, stream>>>(rowptr, col, Tb, Gt, Y1M, Y1T, Y2M, Y2T, sc, t);
  }
  kY<<<rg, rb, 0, stream>>>(q0, C2, sc, Tb, Gt, Y1M, Y1T, a0, NFW);
  kFin<<<rg, rb, 0, stream>>>(rowptr, col, Mb, Tb, Y1M, Y1T, q0, C2, a0, sc, out);
}

// Round 6
// 436.907 us; speedup vs baseline: 5.3345x; 1.1069x over previous
//
#include <hip/hip_runtime.h>
#include <stdint.h>

typedef float    f32x4 __attribute__((ext_vector_type(4)));
typedef uint32_t u32x4 __attribute__((ext_vector_type(4)));

#define NN 5000
#define NE 80000
#define NF 128
#define NT 16
#define TN 10
#define NFW 3
#define NSK 10
#define PW (1.0f/5000.0f)
#define RB 128          // threads per row-block
#define GRX 40          // ceil(NN/RB)

// ---------- workspace layout (bytes) ----------
#define OFF_DEG  0u
#define OFF_RP   20224u
#define OFF_CUR  40448u
#define OFF_COL  60672u      // 320000 B
#define OFF_SC   380672u     // 384 f32 (per-template): [t*16+k]=sabs;
                             // [64+(t*16+k)*4+d]=dots bM,bC,bA,aA; [256+k*4+d]=fin; int[320+k]=ctr
#define SC_FLOATS 384
#define OFF_M    393216u     // f32 16*5000*48
#define OFF_T    4233216u    // f32
#define OFF_G    8073216u    // f32
#define OFF_ATCM 11913216u   // bf16 u32x4 16*5000*16
#define OFF_ATCT 13193216u   // bf16 u32   16*5000*4
#define OFF_ADTM 13513216u
#define OFF_ADTT 14793216u
#define OFF_TNM  15113216u
#define OFF_TNT  16393216u
#define OFF_Y2M  16713216u
#define OFF_Y2T  17993216u   // end 18,313,216

// ---------- helpers ----------
__device__ __forceinline__ uint32_t bfb(float x) {
  uint32_t u = __float_as_uint(x);
  return (u + 0x7fffu + ((u >> 16) & 1u)) >> 16;
}
__device__ __forceinline__ uint32_t pk(float a, float b) { return bfb(a) | (bfb(b) << 16); }
__device__ __forceinline__ float ubl(uint32_t u) { return __uint_as_float(u << 16); }
__device__ __forceinline__ float ubh(uint32_t u) { return __uint_as_float(u & 0xffff0000u); }
__device__ __forceinline__ float sigm(float z) { return 1.f / (1.f + __expf(-z)); }

__device__ __forceinline__ void ld12(const float* p, float* v) {
  f32x4 a = *(const f32x4*)p, b = *(const f32x4*)(p + 4), c = *(const f32x4*)(p + 8);
  v[0]=a[0]; v[1]=a[1]; v[2]=a[2]; v[3]=a[3]; v[4]=b[0]; v[5]=b[1]; v[6]=b[2]; v[7]=b[3];
  v[8]=c[0]; v[9]=c[1];
}
__device__ __forceinline__ void st12(float* p, const float* v) {
  *(f32x4*)p       = (f32x4){v[0], v[1], v[2], v[3]};
  *(f32x4*)(p + 4) = (f32x4){v[4], v[5], v[6], v[7]};
  *(f32x4*)(p + 8) = (f32x4){v[8], v[9], 0.f, 0.f};
}
// bf16 row (8 vals in u32x4 + 2 vals in u32)
__device__ __forceinline__ void ldbf(const u32x4* __restrict__ M4, const uint32_t* __restrict__ M1,
                                     size_t i, float* v) {
  u32x4 A = M4[i]; uint32_t B = M1[i];
  v[0]=ubl(A[0]); v[1]=ubh(A[0]); v[2]=ubl(A[1]); v[3]=ubh(A[1]);
  v[4]=ubl(A[2]); v[5]=ubh(A[2]); v[6]=ubl(A[3]); v[7]=ubh(A[3]);
  v[8]=ubl(B);    v[9]=ubh(B);
}
__device__ __forceinline__ void stbf(u32x4* __restrict__ M4, uint32_t* __restrict__ M1,
                                     size_t i, const float* v) {
  M4[i] = (u32x4){pk(v[0], v[1]), pk(v[2], v[3]), pk(v[4], v[5]), pk(v[6], v[7])};
  M1[i] = pk(v[8], v[9]);
}

__device__ __forceinline__ void gath(const u32x4* __restrict__ YM, const uint32_t* __restrict__ YT,
                                     const int* __restrict__ col, int e0, int e1, float* acc) {
  for (int e = e0; e < e1; ++e) {
    int c = col[e];
    u32x4 A = YM[c]; uint32_t B = YT[c];
    acc[0] += ubl(A[0]); acc[1] += ubh(A[0]); acc[2] += ubl(A[1]); acc[3] += ubh(A[1]);
    acc[4] += ubl(A[2]); acc[5] += ubh(A[2]); acc[6] += ubl(A[3]); acc[7] += ubh(A[3]);
    acc[8] += ubl(B);    acc[9] += ubh(B);
  }
}

__device__ __forceinline__ float get_gamma(const float* __restrict__ sc, int t, int k,
                                           float alpha, float oma) {
  const float* dk = sc + 64 + (size_t)((t - 1) * NT + k) * 4;
  float a_ = -2.f * alpha * dk[3];
  float b_ = oma * dk[0] + alpha * (dk[1] - 4.f * dk[2]);
  return (a_ > 0.f) ? fminf(fmaxf(-b_ / (2.f * a_ + 1e-16f), 0.f), 1.f)
                    : ((a_ + b_ < 0.f) ? 1.f : 0.f);
}

// ---------- setup kernels ----------
__global__ void k_init(char* __restrict__ ws) {
  int g = blockIdx.x * 256 + threadIdx.x;
  if (g < NN) ((int*)(ws + OFF_DEG))[g] = 0;
  int z = g - NN;
  if (z >= 0 && z < SC_FLOATS) ((float*)(ws + OFF_SC))[z] = 0.f;
}
__global__ void k_deg(const int* __restrict__ ei, int* __restrict__ deg) {
  int e = blockIdx.x * 256 + threadIdx.x;
  if (e < NE) atomicAdd(&deg[ei[e]], 1);
}
__global__ void k_scan(const int* __restrict__ deg, int* __restrict__ rowptr, int* __restrict__ cur) {
  __shared__ int scr[1024];
  int tid = threadIdx.x;
  int loc[5], s = 0;
  #pragma unroll
  for (int r = 0; r < 5; ++r) {
    int idx = tid * 5 + r;
    int d = (idx < NN) ? deg[idx] : 0;
    loc[r] = s; s += d;
  }
  scr[tid] = s; __syncthreads();
  for (int off = 1; off < 1024; off <<= 1) {
    int v = scr[tid];
    int u = (tid >= off) ? scr[tid - off] : 0;
    __syncthreads();
    scr[tid] = v + u;
    __syncthreads();
  }
  int base = (tid > 0) ? scr[tid - 1] : 0;
  #pragma unroll
  for (int r = 0; r < 5; ++r) {
    int idx = tid * 5 + r;
    if (idx < NN) { int v = base + loc[r]; rowptr[idx] = v; cur[idx] = v; }
  }
  if (tid == 1023) rowptr[NN] = scr[1023];
}
__global__ void k_fill(const int* __restrict__ ei, int* __restrict__ cur, int* __restrict__ col) {
  int e = blockIdx.x * 256 + threadIdx.x;
  if (e < NE) {
    int s = ei[e];
    int pos = atomicAdd(&cur[s], 1);
    col[pos] = ei[NE + e];
  }
}

// ---------- M build ----------
__global__ void kM(const float* __restrict__ x, const float* __restrict__ F2,
                   float* __restrict__ Mb) {
  __shared__ float ffs[TN];
  const int k = blockIdx.y, tid = threadIdx.x;
  const int i = blockIdx.x * RB + tid;
  const float* Fk = F2 + (size_t)k * TN * NF;
  if (tid < TN) {
    float s = 0.f;
    for (int d = 0; d < NF; ++d) { float f = Fk[tid * NF + d]; s += f * f; }
    ffs[tid] = s;
  }
  __syncthreads();
  if (i >= NN) return;
  const f32x4* xr = (const f32x4*)(x + (size_t)i * NF);
  float acc[TN];
  #pragma unroll
  for (int j = 0; j < TN; ++j) acc[j] = 0.f;
  float xsq = 0.f;
  for (int dc = 0; dc < NF / 4; ++dc) {
    f32x4 xv = xr[dc];
    xsq += xv[0]*xv[0] + xv[1]*xv[1] + xv[2]*xv[2] + xv[3]*xv[3];
    #pragma unroll
    for (int j = 0; j < TN; ++j) {
      const float* Fj = Fk + j * NF + dc * 4;  // uniform -> scalar loads
      acc[j] += xv[0]*Fj[0] + xv[1]*Fj[1] + xv[2]*Fj[2] + xv[3]*Fj[3];
    }
  }
  float v[TN];
  #pragma unroll
  for (int j = 0; j < TN; ++j) v[j] = xsq + ffs[j] - 2.f * acc[j];
  st12(Mb + ((size_t)k * NN + i) * 12, v);
}

// ---------- kYG: T update + running-ATC update + G + sabs (all elementwise) ----------
__global__ void kYG(const int* __restrict__ rowptr, const float* __restrict__ Mb,
                    float* __restrict__ Tb,
                    const u32x4* __restrict__ TnM, const uint32_t* __restrict__ TnT,
                    u32x4* __restrict__ AtM, uint32_t* __restrict__ AtT,
                    const u32x4* __restrict__ AdM, const uint32_t* __restrict__ AdT_,
                    float* __restrict__ Gb, const float* __restrict__ q0,
                    const float* __restrict__ C2g, const float* __restrict__ a0,
                    float* __restrict__ sc, int t) {
  __shared__ float qvs[16], c2qs[16], qC2s[16];
  __shared__ float redl[2];
  const int k = blockIdx.y, tid = threadIdx.x;
  const int i = blockIdx.x * RB + tid;
  const float* C2k = C2g + k * 100;
  if (tid < TN) {
    float mx = -1e30f, e[TN], s = 0.f;
    #pragma unroll
    for (int j = 0; j < TN; ++j) mx = fmaxf(mx, q0[k * TN + j]);
    #pragma unroll
    for (int j = 0; j < TN; ++j) { e[j] = __expf(q0[k * TN + j] - mx); s += e[j]; }
    float inv = 1.f / s;
    qvs[tid] = e[tid] * inv;
    float c2 = 0.f, qc = 0.f;
    #pragma unroll
    for (int l = 0; l < TN; ++l) {
      float c = C2k[tid * TN + l];
      c2 += c * c * e[l] * inv;              // ((C2*C2)@q)[tid]
      qc += e[l] * inv * C2k[l * TN + tid];  // (q^T C2)[tid]
    }
    c2qs[tid] = c2; qC2s[tid] = qc;
  }
  __syncthreads();
  const float alpha = sigm(a0[0]), oma = 1.f - alpha;
  float sabs = 0.f;
  if (i < NN) {
    const int deg = rowptr[i + 1] - rowptr[i];
    const float cc = (float)deg * PW;
    const size_t ro = ((size_t)k * NN + i) * 12;
    const size_t bi = (size_t)k * NN + i;
    float Trow[TN], Arow[TN];
    if (t == 0) {
      // T0 = p q^T ; ATC0 = A (T0 C2) = deg * p * (q^T C2)  [closed form]
      #pragma unroll
      for (int j = 0; j < TN; ++j) { Trow[j] = PW * qvs[j]; Arow[j] = (float)deg * PW * qC2s[j]; }
    } else {
      const float gamma = get_gamma(sc, t, k, alpha, oma);
      float tv[TN], nv[TN], av[TN], dv[TN];
      ld12(Tb + ro, tv);
      ldbf(TnM, TnT, bi, nv);
      ldbf(AtM, AtT, bi, av);
      ldbf(AdM, AdT_, bi, dv);
      #pragma unroll
      for (int j = 0; j < TN; ++j) {
        Trow[j] = tv[j] + gamma * (nv[j] - tv[j]);
        Arow[j] = av[j] + gamma * dv[j];      // ATC_{t} = ATC_{t-1} + g * A(dT C2)  [exact]
      }
    }
    st12(Tb + ro, Trow);
    stbf(AtM, AtT, bi, Arow);
    float mv[TN]; ld12(Mb + ro, mv);
    float Gv[TN];
    #pragma unroll
    for (int j = 0; j < TN; ++j) {
      float G = oma * mv[j] + 2.f * alpha * (cc + c2qs[j] - 2.f * Arow[j]);
      Gv[j] = G; sabs += fabsf(G);
    }
    st12(Gb + ro, Gv);
  }
  #pragma unroll
  for (int o = 32; o; o >>= 1) sabs += __shfl_xor(sabs, o, 64);
  if ((tid & 63) == 0) redl[tid >> 6] = sabs;
  __syncthreads();
  if (tid == 0) atomicAdd(sc + t * NT + k, redl[0] + redl[1]);
}

// ---------- kSink: 10 Sinkhorn iters, E in regs; writes Tn (bf16) ----------
__global__ __launch_bounds__(1024) void kSink(const float* __restrict__ Gb,
                                              u32x4* __restrict__ TnM, uint32_t* __restrict__ TnT,
                                              const float* __restrict__ q0,
                                              const float* __restrict__ sc, int t) {
  __shared__ float red[16 * 16];
  __shared__ float wls[16];
  const int k = blockIdx.x, tid = threadIdx.x;
  const int wid = tid >> 6;
  float qme = 0.f;
  if (tid < TN) {
    float mx = -1e30f, e[TN], s = 0.f;
    #pragma unroll
    for (int j = 0; j < TN; ++j) mx = fmaxf(mx, q0[k * TN + j]);
    #pragma unroll
    for (int j = 0; j < TN; ++j) { e[j] = __expf(q0[k * TN + j] - mx); s += e[j]; }
    qme = e[tid] / s;
  }
  const float reg = 0.05f * sc[t * NT + k] * (1.f / (float)(NN * TN)) + 1e-9f;
  const float invreg = 1.f / reg;
  const float* Gk = Gb + (size_t)k * NN * 12;

  // phase 1: issue ALL G loads (max memory concurrency), then exp in place
  float E[5][TN];
  bool v[5];
  #pragma unroll
  for (int s = 0; s < 5; ++s) {
    int i = s * 1024 + tid;
    v[s] = i < NN;
    if (v[s]) ld12(Gk + (size_t)i * 12, E[s]);
  }
  #pragma unroll
  for (int s = 0; s < 5; ++s) {
    if (v[s]) {
      float mn = E[s][0];
      #pragma unroll
      for (int j = 1; j < TN; ++j) mn = fminf(mn, E[s][j]);
      #pragma unroll
      for (int j = 0; j < TN; ++j) E[s][j] = __expf(-(E[s][j] - mn) * invreg);
    } else {
      #pragma unroll
      for (int j = 0; j < TN; ++j) E[s][j] = 0.f;
    }
  }

  float wlr[TN], wpr[TN];
  #pragma unroll
  for (int j = 0; j < TN; ++j) { wlr[j] = 1.f; wpr[j] = 1.f; }
  for (int it = 0; it < NSK; ++it) {
    float csl[TN];
    #pragma unroll
    for (int j = 0; j < TN; ++j) csl[j] = 0.f;
    #pragma unroll
    for (int s = 0; s < 5; ++s) {
      float dot = 0.f;
      #pragma unroll
      for (int j = 0; j < TN; ++j) dot += E[s][j] * wlr[j];
      float u = PW * __builtin_amdgcn_rcpf(fmaxf(dot, 1e-35f));
      #pragma unroll
      for (int j = 0; j < TN; ++j) csl[j] += E[s][j] * u;
    }
    #pragma unroll
    for (int j = 0; j < TN; ++j) {
      float vv = csl[j];
      #pragma unroll
      for (int o = 32; o; o >>= 1) vv += __shfl_xor(vv, o, 64);
      if ((tid & 63) == j) red[wid * 16 + j] = vv;
    }
    __syncthreads();
    if (tid < TN) {
      float s = 0.f;
      #pragma unroll
      for (int w = 0; w < 16; ++w) s += red[w * 16 + tid];
      wls[tid] = qme * __builtin_amdgcn_rcpf(fmaxf(s, 1e-35f));
    }
    __syncthreads();
    #pragma unroll
    for (int j = 0; j < TN; ++j) { wpr[j] = wlr[j]; wlr[j] = wls[j]; }
  }
  // Tn = u(wp) * E * wl -> bf16
  u32x4* TM = TnM + (size_t)k * NN;
  uint32_t* TT = TnT + (size_t)k * NN;
  #pragma unroll
  for (int s = 0; s < 5; ++s) {
    if (v[s]) {
      int i = s * 1024 + tid;
      float dot = 0.f;
      #pragma unroll
      for (int j = 0; j < TN; ++j) dot += E[s][j] * wpr[j];
      float u = PW * __builtin_amdgcn_rcpf(fmaxf(dot, 1e-35f));
      float tn[TN];
      #pragma unroll
      for (int j = 0; j < TN; ++j) tn[j] = u * E[s][j] * wlr[j];
      stbf(TM, TT, (size_t)i, tn);
    }
  }
}

// ---------- kDT: dT = Tn - T, bM/bC dots, Y2 = dT@C2 (bf16) ----------
__global__ void kDT(const int* __restrict__ rowptr, const float* __restrict__ Mb,
                    const float* __restrict__ Tb,
                    const u32x4* __restrict__ TnM, const uint32_t* __restrict__ TnT,
                    const float* __restrict__ q0, const float* __restrict__ C2g,
                    u32x4* __restrict__ Y2M, uint32_t* __restrict__ Y2T,
                    float* __restrict__ sc, int t) {
  __shared__ float c2qs[16];
  __shared__ float redl[4];
  const int k = blockIdx.y, tid = threadIdx.x;
  const int i = blockIdx.x * RB + tid;
  const float* C2k = C2g + k * 100;
  if (tid < TN) {
    float mx = -1e30f, e[TN], s = 0.f;
    #pragma unroll
    for (int j = 0; j < TN; ++j) mx = fmaxf(mx, q0[k * TN + j]);
    #pragma unroll
    for (int j = 0; j < TN; ++j) { e[j] = __expf(q0[k * TN + j] - mx); s += e[j]; }
    float inv = 1.f / s, c2 = 0.f;
    #pragma unroll
    for (int l = 0; l < TN; ++l) { float c = C2k[tid * TN + l]; c2 += c * c * e[l] * inv; }
    c2qs[tid] = c2;
  }
  __syncthreads();
  float bM = 0.f, bC = 0.f;
  if (i < NN) {
    const size_t ro = ((size_t)k * NN + i) * 12;
    const size_t bi = (size_t)k * NN + i;
    float tv[TN], nv[TN], mv[TN], d[TN];
    ld12(Tb + ro, tv); ldbf(TnM, TnT, bi, nv); ld12(Mb + ro, mv);
    float cc = (float)(rowptr[i + 1] - rowptr[i]) * PW;
    #pragma unroll
    for (int j = 0; j < TN; ++j) {
      d[j] = nv[j] - tv[j];
      bM += mv[j] * d[j];
      bC += (cc + c2qs[j]) * d[j];
    }
    // Y2 = dT @ C2 (bf16)
    float y[TN];
    #pragma unroll
    for (int j = 0; j < TN; ++j) {
      float s = 0.f;
      #pragma unroll
      for (int l = 0; l < TN; ++l) s += d[l] * C2k[l * TN + j];
      y[j] = s;
    }
    stbf(Y2M + (size_t)k * NN, Y2T + (size_t)k * NN, (size_t)i, y);
  }
  #pragma unroll
  for (int o = 32; o; o >>= 1) { bM += __shfl_xor(bM, o, 64); bC += __shfl_xor(bC, o, 64); }
  if ((tid & 63) == 0) { int w = tid >> 6; redl[w * 2] = bM; redl[w * 2 + 1] = bC; }
  __syncthreads();
  if (tid == 0) {
    float* dk = sc + 64 + (size_t)(t * NT + k) * 4;
    atomicAdd(dk + 0, redl[0] + redl[2]);
    atomicAdd(dk + 1, redl[1] + redl[3]);
  }
}

// ---------- kA: gather Y2 -> adt; bA = ATC.dT, aA = adt.dT; store adt ----------
__global__ void kA(const int* __restrict__ rowptr, const int* __restrict__ col,
                   const float* __restrict__ Tb,
                   const u32x4* __restrict__ TnM, const uint32_t* __restrict__ TnT,
                   const u32x4* __restrict__ AtM, const uint32_t* __restrict__ AtT,
                   const u32x4* __restrict__ Y2M, const uint32_t* __restrict__ Y2T,
                   u32x4* __restrict__ AdM, uint32_t* __restrict__ AdT_,
                   float* __restrict__ sc, int t) {
  __shared__ float redl[4];
  const int k = blockIdx.y, tid = threadIdx.x;
  const int i = blockIdx.x * RB + tid;
  float bA = 0.f, aacc = 0.f;
  if (i < NN) {
    const size_t ro = ((size_t)k * NN + i) * 12;
    const size_t bi = (size_t)k * NN + i;
    float tv[TN], nv[TN], av[TN];
    ld12(Tb + ro, tv); ldbf(TnM, TnT, bi, nv); ldbf(AtM, AtT, bi, av);
    int e0 = rowptr[i], e1 = rowptr[i + 1];
    float adt[TN];
    #pragma unroll
    for (int j = 0; j < TN; ++j) adt[j] = 0.f;
    gath(Y2M + (size_t)k * NN, Y2T + (size_t)k * NN, col, e0, e1, adt);
    #pragma unroll
    for (int j = 0; j < TN; ++j) {
      float d = nv[j] - tv[j];
      bA += av[j] * d;
      aacc += adt[j] * d;
    }
    stbf(AdM, AdT_, bi, adt);
  }
  #pragma unroll
  for (int o = 32; o; o >>= 1) { bA += __shfl_xor(bA, o, 64); aacc += __shfl_xor(aacc, o, 64); }
  if ((tid & 63) == 0) { int w = tid >> 6; redl[w * 2] = bA; redl[w * 2 + 1] = aacc; }
  __syncthreads();
  if (tid == 0) {
    float* dk = sc + 64 + (size_t)(t * NT + k) * 4;
    atomicAdd(dk + 2, redl[0] + redl[2]);
    atomicAdd(dk + 3, redl[1] + redl[3]);
  }
}

// ---------- kFinYG: final T/ATC update (in regs) + distance, all elementwise ----------
__global__ void kFinYG(const int* __restrict__ rowptr, const float* __restrict__ Mb,
                       const float* __restrict__ Tb,
                       const u32x4* __restrict__ TnM, const uint32_t* __restrict__ TnT,
                       const u32x4* __restrict__ AtM, const uint32_t* __restrict__ AtT,
                       const u32x4* __restrict__ AdM, const uint32_t* __restrict__ AdT_,
                       const float* __restrict__ q0, const float* __restrict__ C2g,
                       const float* __restrict__ a0, float* __restrict__ sc,
                       float* __restrict__ out) {
  __shared__ float c2qs[16];
  __shared__ float redl[6];
  const int k = blockIdx.y, tid = threadIdx.x;
  const int i = blockIdx.x * RB + tid;
  const float* C2k = C2g + k * 100;
  if (tid < TN) {
    float mx = -1e30f, e[TN], s = 0.f;
    #pragma unroll
    for (int j = 0; j < TN; ++j) mx = fmaxf(mx, q0[k * TN + j]);
    #pragma unroll
    for (int j = 0; j < TN; ++j) { e[j] = __expf(q0[k * TN + j] - mx); s += e[j]; }
    float inv = 1.f / s, c2 = 0.f;
    #pragma unroll
    for (int l = 0; l < TN; ++l) { float c = C2k[tid * TN + l]; c2 += c * c * e[l] * inv; }
    c2qs[tid] = c2;
  }
  __syncthreads();
  const float alpha = sigm(a0[0]), oma = 1.f - alpha;
  const float gamma = get_gamma(sc, NFW, k, alpha, oma);
  float d1 = 0.f, d2 = 0.f, d3 = 0.f;
  if (i < NN) {
    const size_t ro = ((size_t)k * NN + i) * 12;
    const size_t bi = (size_t)k * NN + i;
    float tv[TN], nv[TN], av[TN], dv[TN], mv[TN];
    ld12(Tb + ro, tv); ldbf(TnM, TnT, bi, nv);
    ldbf(AtM, AtT, bi, av); ldbf(AdM, AdT_, bi, dv);
    ld12(Mb + ro, mv);
    float cc = (float)(rowptr[i + 1] - rowptr[i]) * PW;
    #pragma unroll
    for (int j = 0; j < TN; ++j) {
      float Tf = tv[j] + gamma * (nv[j] - tv[j]);
      float Af = av[j] + gamma * dv[j];
      d1 += mv[j] * Tf;
      d2 += (cc + c2qs[j]) * Tf;
      d3 += Af * Tf;
    }
  }
  #pragma unroll
  for (int o = 32; o; o >>= 1) {
    d1 += __shfl_xor(d1, o, 64); d2 += __shfl_xor(d2, o, 64); d3 += __shfl_xor(d3, o, 64);
  }
  if ((tid & 63) == 0) {
    int w = tid >> 6;
    redl[w * 3] = d1; redl[w * 3 + 1] = d2; redl[w * 3 + 2] = d3;
  }
  __syncthreads();
  float* fk = sc + 256 + k * 4;
  if (tid == 0) {
    atomicAdd(fk + 0, redl[0] + redl[3]);
    atomicAdd(fk + 1, redl[1] + redl[4]);
    atomicAdd(fk + 2, redl[2] + redl[5]);
  }
  asm volatile("s_waitcnt vmcnt(0)" ::: "memory");
  __syncthreads();
  if (tid == 0) {
    int* ctr = (int*)sc + 320 + k;
    int old = __hip_atomic_fetch_add(ctr, 1, __ATOMIC_RELAXED, __HIP_MEMORY_SCOPE_AGENT);
    if (old == GRX - 1) {
      float f0 = __hip_atomic_fetch_add(fk + 0, 0.f, __ATOMIC_RELAXED, __HIP_MEMORY_SCOPE_AGENT);
      float f1 = __hip_atomic_fetch_add(fk + 1, 0.f, __ATOMIC_RELAXED, __HIP_MEMORY_SCOPE_AGENT);
      float f2 = __hip_atomic_fetch_add(fk + 2, 0.f, __ATOMIC_RELAXED, __HIP_MEMORY_SCOPE_AGENT);
      out[k] = oma * f0 + alpha * (f1 - 2.f * f2);
    }
  }
}

extern "C" void kernel_launch(void* const* d_in, const int* in_sizes, int n_in,
                              void* d_out, int out_size, void* d_ws, size_t ws_size,
                              hipStream_t stream) {
  const float* x  = (const float*)d_in[0];
  const int*   ei = (const int*)d_in[1];
  const float* C2 = (const float*)d_in[2];
  const float* F2 = (const float*)d_in[3];
  const float* q0 = (const float*)d_in[4];
  const float* a0 = (const float*)d_in[5];
  float* out = (float*)d_out;

  char* ws = (char*)d_ws;
  int* deg    = (int*)(ws + OFF_DEG);
  int* rowptr = (int*)(ws + OFF_RP);
  int* cur    = (int*)(ws + OFF_CUR);
  int* col    = (int*)(ws + OFF_COL);
  float* sc   = (float*)(ws + OFF_SC);
  float* Mb   = (float*)(ws + OFF_M);
  float* Tb   = (float*)(ws + OFF_T);
  float* Gb   = (float*)(ws + OFF_G);
  u32x4* AtM  = (u32x4*)(ws + OFF_ATCM);
  uint32_t* AtT = (uint32_t*)(ws + OFF_ATCT);
  u32x4* AdM  = (u32x4*)(ws + OFF_ADTM);
  uint32_t* AdT_ = (uint32_t*)(ws + OFF_ADTT);
  u32x4* TnM  = (u32x4*)(ws + OFF_TNM);
  uint32_t* TnT = (uint32_t*)(ws + OFF_TNT);
  u32x4* Y2M  = (u32x4*)(ws + OFF_Y2M);
  uint32_t* Y2T = (uint32_t*)(ws + OFF_Y2T);

  const dim3 rg(GRX, NT), rb(RB);

  k_init<<<(NN + SC_FLOATS + 255) / 256, 256, 0, stream>>>(ws);
  k_deg<<<(NE + 255) / 256, 256, 0, stream>>>(ei, deg);
  k_scan<<<1, 1024, 0, stream>>>(deg, rowptr, cur);
  k_fill<<<(NE + 255) / 256, 256, 0, stream>>>(ei, cur, col);
  kM<<<rg, rb, 0, stream>>>(x, F2, Mb);

  for (int t = 0; t < NFW; ++t) {
    kYG<<<rg, rb, 0, stream>>>(rowptr, Mb, Tb, TnM, TnT, AtM, AtT, AdM, AdT_,
                               Gb, q0, C2, a0, sc, t);
    kSink<<<NT, 1024, 0, stream>>>(Gb, TnM, TnT, q0, sc, t);
    kDT<<<rg, rb, 0, stream>>>(rowptr, Mb, Tb, TnM, TnT, q0, C2, Y2M, Y2T, sc, t);
    kA<<<rg, rb, 0, stream>>>(rowptr, col, Tb, TnM, TnT, AtM, AtT, Y2M, Y2T,
                              AdM, AdT_, sc, t);
  }
  kFinYG<<<rg, rb, 0, stream>>>(rowptr, Mb, Tb, TnM, TnT, AtM, AtT, AdM, AdT_,
                                q0, C2, a0, sc, out);
}